// Round 13
// baseline (3696.497 us; speedup 1.0000x reference)
//
#include <hip/hip_runtime.h>
#include <hip/hip_bf16.h>
#include <stdint.h>
#include <stddef.h>

// ============================================================================
// PPOAgent fused pipeline for MI355X (gfx950) — v13
// v13 k3r: 8-gq geometry (96 loads/step; correctness verified v10-v12) written
// in v7's EXACT no-spill register idioms:
//  - four NAMED 1-D arrays acc0..acc3 / creg0..creg3 (no 2-D aggregates)
//  - bias pre-initialized into acc BEFORE the kt loop (no if(kt==0) branch)
//  - named bf0..bf3 row fragments, serial one-wf loads, s_barrier每4kt
// Spill-delta isolation: v10/v11/v12 (2-D acc + in-loop cond init) all spilled
// 3.5GB; v7 (1-D named + pre-init) did not. This is the controlled test.
// Decision rule: WRITE~265MB -> fixed; WRITE>1GB -> revert to exact R7 next.
// ============================================================================

typedef short bf16x8 __attribute__((ext_vector_type(8)));
typedef short bf16x4 __attribute__((ext_vector_type(4)));
typedef float f32x4  __attribute__((ext_vector_type(4)));

#define LOG2E 1.44269504088896340736f

__device__ __forceinline__ float fexp2(float x){ return __builtin_amdgcn_exp2f(x); }
__device__ __forceinline__ float frcpf_(float x){ return __builtin_amdgcn_rcpf(x); }
__device__ __forceinline__ float fsig(float x){ return frcpf_(1.0f + fexp2(-x*LOG2E)); }
__device__ __forceinline__ float ftanh_(float x){ return 1.0f - 2.0f*frcpf_(1.0f + fexp2(x*(2.0f*LOG2E))); }

__device__ __forceinline__ short f2bf(float f){
  unsigned u = __builtin_bit_cast(unsigned, f);
  u += 0x7fffu + ((u>>16)&1u);
  return (short)(u>>16);
}
__device__ __forceinline__ float bf2f(short h){
  unsigned u = ((unsigned)(unsigned short)h)<<16;
  return __builtin_bit_cast(float, u);
}

// ---------------- workspace layout (bytes) ----------------
static constexpr size_t WS_WMAIN  = 0;          // packed [Wih;Whh] A-frag stream, 768KB
static constexpr size_t WS_WA1P   = 786432;
static constexpr size_t WS_WV1P   = 851968;
static constexpr size_t WS_WA2P   = 917504;
static constexpr size_t WS_WV2P   = 950272;
static constexpr size_t WS_BMAIN  = 983040;     // 1024 f32 bias (j-major, e-minor)
static constexpr size_t WS_META   = 1048576;    // nSegs@+0 ; maskMode@+16 ; hist@+4096 ; curs@+12288
static constexpr size_t WS_SEGS   = 1081344;    // 524288 u32
static constexpr size_t WS_SORTED = 3178496;    // 524288 u32  (end 5275648)
static constexpr size_t WS_HID    = 5275648;    // 524288 x 256 bf16 = 268435456
static constexpr size_t WS_NEED_SPLIT = WS_HID + 268435456; // 273711104

// ============================================================================
// K0a (8-gq layout, verified v10-v12): chunk (kt,gq8):
//   addr(short) = (kt*8+gq)*4096 + nt*512 + lane*8 ;  nt in 0..7
// element: slot=lane&15 -> ug=slot>>2, eg=slot&3 ; j = gq*32+ug*8+nt ;
//   g = eg*256+j ; k = kt*32 + (lane>>4)*8 + jj.   bias: bp[j*4+e].
// ============================================================================
__global__ void k0a_packmain(const float* __restrict__ wih, const float* __restrict__ whh,
                             const float* __restrict__ bih, const float* __restrict__ bhh,
                             short* __restrict__ wp, float* __restrict__ bp)
{
  int tidg = blockIdx.x*512 + threadIdx.x;     // 0..49151
  {
    int lane = tidg & 63;
    int nt   = (tidg>>6) & 7;
    int ci   = tidg>>9;                        // 0..95
    int kt = ci>>3, gq = ci&7;
    int slot = lane & 15;
    int ug = slot >> 2, eg = slot & 3;
    int j  = gq*32 + ug*8 + nt;
    int g  = eg*256 + j;
    int k0 = kt*32 + (lane>>4)*8;
    bf16x8 ov;
#pragma unroll
    for (int jj=0;jj<8;++jj){
      int k = k0 + jj;
      float v = (k < 128) ? wih[(size_t)g*128 + k] : whh[(size_t)g*256 + (k-128)];
      ov[jj] = f2bf(v);
    }
    *(bf16x8*)(wp + (size_t)tidg*8) = ov;
  }
  if (tidg < 1024) {
    int j = tidg>>2, e = tidg&3;
    int g = e*256 + j;
    bp[tidg] = bih[g] + bhh[g];
  }
}

// K0a (v4/v7 layout) — only for the small-ws fused fallback path.
__global__ void k0a_packmain_v4(const float* __restrict__ wih, const float* __restrict__ whh,
                                const float* __restrict__ bih, const float* __restrict__ bhh,
                                short* __restrict__ wp, float* __restrict__ bp)
{
  int tidg = blockIdx.x*512 + threadIdx.x;
  {
    int lane = tidg & 63;
    int nt   = (tidg>>6) & 15;
    int ci   = tidg>>10;
    int kt = ci>>2, gq = ci&3;
    int gs = lane & 15;
    int ug = gs>>2, eg = gs&3;
    int j  = gq*64 + ug*16 + nt;
    int g  = eg*256 + j;
    int k0 = kt*32 + (lane>>4)*8;
    bf16x8 ov;
#pragma unroll
    for (int jj=0;jj<8;++jj){
      int k = k0 + jj;
      float v = (k < 128) ? wih[(size_t)g*128 + k] : whh[(size_t)g*256 + (k-128)];
      ov[jj] = f2bf(v);
    }
    *(bf16x8*)(wp + (size_t)tidg*8) = ov;
  }
  if (tidg < 1024) {
    int cgp = tidg;
    int gq = cgp>>8, nt = (cgp>>4)&15, ug = (cgp>>2)&3, eg = cgp&3;
    int g = eg*256 + gq*64 + ug*16 + nt;
    bp[cgp] = bih[g] + bhh[g];
  }
}

// K0b: pack head weights (N x K row-major -> frag stream)
__global__ void k0b_packheads(const float* __restrict__ wa1, const float* __restrict__ wv1,
                              const float* __restrict__ wa2, const float* __restrict__ wv2,
                              short* __restrict__ wa1p, short* __restrict__ wv1p,
                              short* __restrict__ wa2p, short* __restrict__ wv2p)
{
  int p = blockIdx.x*512 + threadIdx.x;     // 0..12287
  const float* src; short* dst; int K; int pl;
  if (p < 4096)       { src=wa1; dst=wa1p; K=256; pl=p; }
  else if (p < 8192)  { src=wv1; dst=wv1p; K=256; pl=p-4096; }
  else if (p < 10240) { src=wa2; dst=wa2p; K=128; pl=p-8192; }
  else                { src=wv2; dst=wv2p; K=128; pl=p-10240; }
  int lane = pl & 63;
  int f    = pl >> 6;
  int nt   = f & 7;
  int kt   = f >> 3;
  int n  = nt*16 + (lane&15);
  int k0 = kt*32 + (lane>>4)*8;
  bf16x8 ov;
#pragma unroll
  for (int j=0;j<8;++j) ov[j] = f2bf(src[(size_t)n*K + k0 + j]);
  *(bf16x8*)(dst + (size_t)pl*8) = ov;
}

// K1: detect mask storage layout (byte-bools vs int32).
__global__ void k1_maskmode(const unsigned char* __restrict__ mask, uint32_t* __restrict__ flag)
{
  int i = blockIdx.x*256 + threadIdx.x;
  uint32_t v = ((i & 3) != 0) ? (uint32_t)mask[i] : 0u;
  if (v) atomicOr((unsigned int*)flag, 1u);
}

// ============================================================================
// K2a-d: segment extraction + LDS-histogram bucket sort (desc). Unchanged.
// ============================================================================
__global__ void k2a_segments(const int* __restrict__ done, uint32_t* __restrict__ segs,
                             uint32_t* __restrict__ nSegs)
{
  const int b = blockIdx.x;
  const int tid = threadIdx.x;
  __shared__ uint16_t starts[1025];
  __shared__ uint32_t cnts[256];
  __shared__ uint32_t basePos;

  uint32_t my[4]; int myn = 0;
  int t0 = tid*4;
#pragma unroll
  for (int i=0;i<4;++i){
    int t = t0 + i;
    int d = done[(size_t)t*512 + b];
    if (t == 0 || d != 0) my[myn++] = (uint32_t)t;
  }
  cnts[tid] = (uint32_t)myn;
  __syncthreads();
  for (int off=1; off<256; off<<=1){
    uint32_t v = (tid >= off) ? cnts[tid-off] : 0u;
    __syncthreads();
    cnts[tid] += v;
    __syncthreads();
  }
  uint32_t myBase = cnts[tid] - (uint32_t)myn;
  uint32_t ns = cnts[255];
  for (int i=0;i<myn;++i) starts[myBase+i] = (uint16_t)my[i];
  if (tid == 0) {
    starts[ns] = 1024;
    basePos = atomicAdd((unsigned int*)nSegs, ns);
  }
  __syncthreads();
  for (uint32_t i = tid; i < ns; i += 256) {
    uint32_t st = starts[i];
    uint32_t ln = (uint32_t)starts[i+1] - st;
    segs[basePos + i] = ((ln-1u)<<19) | (st<<9) | (uint32_t)b;
  }
}

__global__ void k2b_hist(const uint32_t* __restrict__ segs, const uint32_t* __restrict__ nSegs,
                         uint32_t* __restrict__ hist)
{
  __shared__ uint32_t lh[1025];
  const uint32_t n = *nSegs;
  for (int i = threadIdx.x; i < 1025; i += 512) lh[i] = 0;
  __syncthreads();
  for (uint32_t i = blockIdx.x*512u + threadIdx.x; i < n; i += gridDim.x*512u) {
    uint32_t ln = ((segs[i]>>19)&1023u) + 1u;
    atomicAdd(&lh[ln], 1u);
  }
  __syncthreads();
  for (int i = threadIdx.x; i < 1025; i += 512)
    if (lh[i]) atomicAdd((unsigned int*)&hist[i], lh[i]);
}

__global__ void k2c_scan(const uint32_t* __restrict__ hist, uint32_t* __restrict__ curs)
{
  __shared__ uint32_t s[1024];
  const int tid = threadIdx.x;
  uint32_t own = hist[tid+1];
  s[tid] = own;
  __syncthreads();
  for (int off=1; off<1024; off<<=1){
    uint32_t v = (tid+off < 1024) ? s[tid+off] : 0u;
    __syncthreads();
    s[tid] += v;
    __syncthreads();
  }
  curs[tid+1] = s[tid] - own;
  if (tid == 0) curs[0] = 0;
}

__global__ void k2d_scatter(const uint32_t* __restrict__ segs, const uint32_t* __restrict__ nSegs,
                            uint32_t* __restrict__ curs, uint32_t* __restrict__ sorted)
{
  __shared__ uint32_t lh[1025];
  __shared__ uint32_t base[1025];
  const uint32_t n = *nSegs;
  const uint32_t chunk = (n + 127u) >> 7;          // gridDim.x == 128
  const uint32_t lo = blockIdx.x * chunk;
  const uint32_t hi = (lo + chunk < n) ? (lo + chunk) : n;
  for (int i = threadIdx.x; i < 1025; i += 512) lh[i] = 0;
  __syncthreads();
  for (uint32_t i = lo + threadIdx.x; i < hi; i += 512u) {
    uint32_t ln = ((segs[i]>>19)&1023u) + 1u;
    atomicAdd(&lh[ln], 1u);
  }
  __syncthreads();
  for (int i = threadIdx.x; i < 1025; i += 512) {
    uint32_t c = lh[i];
    if (c) base[i] = atomicAdd((unsigned int*)&curs[i], c);
    lh[i] = 0;
  }
  __syncthreads();
  for (uint32_t i = lo + threadIdx.x; i < hi; i += 512u) {
    uint32_t r = segs[i];
    uint32_t ln = ((r>>19)&1023u) + 1u;
    uint32_t pos = base[ln] + atomicAdd(&lh[ln], 1u);
    sorted[pos] = r;
  }
}

// ---- v13 cell/init macros: all-constant indexing on NAMED 1-D arrays ----
#define CINIT13(CREG, R4) do {                                                \
  const int r_ = (R4)*16 + cl;                                                \
  const uint32_t mb_ = meta[r_], mst_ = meta[64+r_], mln_ = meta[128+r_];     \
  const bool init_ = (mln_ > 0u) && (mst_ == 0u) && (done[mb_] == 0);         \
  f32x4 c01_ = init_ ? *(const f32x4*)(c0 + (size_t)mb_*256u + jbL)           \
                     : (f32x4){0.f,0.f,0.f,0.f};                              \
  f32x4 c23_ = init_ ? *(const f32x4*)(c0 + (size_t)mb_*256u + jbL + 4)       \
                     : (f32x4){0.f,0.f,0.f,0.f};                              \
  _Pragma("unroll")                                                           \
  for (int q_=0;q_<4;++q_){ CREG[q_]=c01_[q_]; CREG[4+q_]=c23_[q_]; }         \
} while(0)

#define CELL13(ACC, CREG, R4) do {                                            \
  const int r_ = (R4)*16 + cl;                                                \
  const uint32_t mb_ = meta[r_], mst_ = meta[64+r_], mln_ = meta[128+r_];     \
  const bool fin_ = (it == (int)mln_ - 1) && (mst_ + mln_ == 1024u) && (mln_ > 0u); \
  bf16x8 hvv_;                                                                \
  _Pragma("unroll")                                                           \
  for (int q_=0;q_<8;++q_) {                                                  \
    f32x4 gA_ = ACC[q_];                                                      \
    float i0_=fsig(gA_[0]), f0_=fsig(gA_[1]), g0_=ftanh_(gA_[2]), o0_=fsig(gA_[3]); \
    float c_ = f0_*CREG[q_] + i0_*g0_; CREG[q_] = c_;                         \
    float h_ = o0_*ftanh_(c_);                                                \
    hvv_[q_] = f2bf(h_);                                                      \
    if (fin_) { hnOut[(size_t)mb_*256u + jbL + q_] = h_;                      \
                cnOut[(size_t)mb_*256u + jbL + q_] = c_; }                    \
  }                                                                           \
  *(bf16x8*)(Alds + r_*768 + ((256 + 2*jbL) ^ swc)) = hvv_;                   \
} while(0)

// ============================================================================
// K3r v13: 512 thr = 8 waves; wave wv = gq owns gates [gq*128,+128) x 64 rows.
// acc0..acc3 (named 1-D, 128 f32 -> AGPR), bias pre-init, serial wf loads.
// ============================================================================
__global__ __launch_bounds__(512, 2) void k3r_lstm(
    const float* __restrict__ x, const int* __restrict__ done,
    const float* __restrict__ h0, const float* __restrict__ c0,
    const short* __restrict__ wpack, const float* __restrict__ bpack,
    const uint32_t* __restrict__ sortedSegs, const uint32_t* __restrict__ nSegsPtr,
    short* __restrict__ hidden, float* __restrict__ hnOut, float* __restrict__ cnOut)
{
  __shared__ char smem[54016];
  char* Alds = smem;                            // [64][768] swizzled
  float* biasL = (float*)(smem + 49152);        // 1024 f32 (j-major, e-minor)
  uint32_t* meta = (uint32_t*)(smem + 53248);   // b[64], st@+64, len@+128

  const int tid  = threadIdx.x;
  const int lane = tid & 63;
  const int wv   = tid >> 6;        // 0..7 = gq
  const int cl   = lane & 15;
  const int u    = lane >> 4;
  const int ku   = u*16;
  const int swc  = (cl & 7) << 4;
  const int jbL  = wv*32 + u*8;     // lane's j base (q adds 0..7)

  const int row8 = tid >> 3;        // 0..63
  const int oct  = tid & 7;
  const int rsw8 = (row8 & 7) << 4;

  biasL[tid]       = bpack[tid];
  biasL[512 + tid] = bpack[512 + tid];

  const uint32_t nSegs = *nSegsPtr;
  const uint32_t nGroups = (nSegs + 63u) >> 6;

  for (uint32_t g = blockIdx.x; g < nGroups; g += gridDim.x) {
    __syncthreads();                       // prev group fully consumed
    if (tid < 64) {
      uint32_t idx = g*64u + (uint32_t)tid;
      uint32_t b=0, st=0, ln=0;
      if (idx < nSegs) {
        uint32_t r = sortedSegs[idx];
        b = r & 511u; st = (r>>9)&1023u; ln = ((r>>19)&1023u) + 1u;
      }
      meta[tid] = b; meta[64+tid] = st; meta[128+tid] = ln;
    }
    __syncthreads();

    const uint32_t mb8  = meta[row8];
    const uint32_t mst8 = meta[64+row8];
    const uint32_t mln8 = meta[128+row8];
    const int maxLen = (int)meta[128];   // desc sort -> slot 0 max

    // ---- group init: x(iter0) [0,256) + FULL h [256,768) into A-tile ----
    {
      const bool act = (mln8 > 0u);
      float xf[16];
      if (act) {
        const float4* xp = (const float4*)(x + ((size_t)mst8*512u + mb8)*128u + (size_t)oct*16u);
#pragma unroll
        for (int i=0;i<4;++i){ float4 t4 = xp[i]; xf[4*i]=t4.x; xf[4*i+1]=t4.y; xf[4*i+2]=t4.z; xf[4*i+3]=t4.w; }
      } else {
#pragma unroll
        for (int i=0;i<16;++i) xf[i]=0.0f;
      }
      bf16x8 v0, v1;
#pragma unroll
      for (int j=0;j<8;++j){ v0[j]=f2bf(xf[j]); v1[j]=f2bf(xf[8+j]); }
      *(bf16x8*)(Alds + row8*768 + ((oct*32     ) ^ rsw8)) = v0;
      *(bf16x8*)(Alds + row8*768 + ((oct*32 + 16) ^ rsw8)) = v1;

      const bool useInit = act && (mst8 == 0u) && (done[mb8] == 0);
      float hf[32];
      if (useInit) {
        const float4* hp = (const float4*)(h0 + (size_t)mb8*256u + (size_t)oct*32u);
#pragma unroll
        for (int i=0;i<8;++i){ float4 t4 = hp[i]; hf[4*i]=t4.x; hf[4*i+1]=t4.y; hf[4*i+2]=t4.z; hf[4*i+3]=t4.w; }
      } else {
#pragma unroll
        for (int i=0;i<32;++i) hf[i]=0.0f;
      }
#pragma unroll
      for (int q=0;q<4;++q){
        bf16x8 hv;
#pragma unroll
        for (int j=0;j<8;++j) hv[j]=f2bf(hf[q*8+j]);
        *(bf16x8*)(Alds + row8*768 + ((256 + oct*64 + q*16) ^ rsw8)) = hv;
      }
    }

    // ---- c state init (named 1-D arrays, constant indices) ----
    float creg0[8], creg1[8], creg2[8], creg3[8];
    CINIT13(creg0, 0);
    CINIT13(creg1, 1);
    CINIT13(creg2, 2);
    CINIT13(creg3, 3);

    for (int it = 0; it < maxLen; ++it) {
      __syncthreads();                   // S1: A-tile (x_t, h_{t-1}) ready

      // ---- deferred hidden store of h_{t-1} ----
      if (it >= 1 && (uint32_t)(it-1) < mln8) {
        const size_t grow = (size_t)(mst8 + (uint32_t)(it-1))*512u + mb8;
        short* hp = hidden + grow*256u + (size_t)oct*32u;
#pragma unroll
        for (int q=0;q<4;++q)
          *(bf16x8*)(hp + q*8) = *(const bf16x8*)(Alds + row8*768 + ((256 + oct*64 + q*16) ^ rsw8));
      }

      // ---- GEMM: bias pre-init (v7 idiom), serial wf loads ----
      f32x4 acc0[8], acc1[8], acc2[8], acc3[8];
#pragma unroll
      for (int q=0;q<8;++q){
        f32x4 bv = *(const f32x4*)(biasL + (jbL + q)*4);
        acc0[q]=bv; acc1[q]=bv; acc2[q]=bv; acc3[q]=bv;
      }
      for (int kt=0; kt<12; ++kt) {
        if ((kt & 3) == 0) __builtin_amdgcn_s_barrier();
        const short* wkt = wpack + (size_t)(kt*8 + wv)*4096 + lane*8;
        bf16x8 bf0 = *(const bf16x8*)(Alds + (     cl)*768 + ((kt*64 + ku) ^ swc));
        bf16x8 bf1 = *(const bf16x8*)(Alds + (16 + cl)*768 + ((kt*64 + ku) ^ swc));
        bf16x8 bf2 = *(const bf16x8*)(Alds + (32 + cl)*768 + ((kt*64 + ku) ^ swc));
        bf16x8 bf3 = *(const bf16x8*)(Alds + (48 + cl)*768 + ((kt*64 + ku) ^ swc));
#pragma unroll
        for (int q=0;q<8;++q) {
          const bf16x8 wf = *(const bf16x8*)(wkt + q*512);
          acc0[q] = __builtin_amdgcn_mfma_f32_16x16x32_bf16(wf, bf0, acc0[q], 0,0,0);
          acc1[q] = __builtin_amdgcn_mfma_f32_16x16x32_bf16(wf, bf1, acc1[q], 0,0,0);
          acc2[q] = __builtin_amdgcn_mfma_f32_16x16x32_bf16(wf, bf2, acc2[q], 0,0,0);
          acc3[q] = __builtin_amdgcn_mfma_f32_16x16x32_bf16(wf, bf3, acc3[q], 0,0,0);
        }
      }

      // ---- x prefetch for it+1 (bf16 immediately: 8 regs) ----
      bf16x8 xpre0, xpre1;
      {
        const bool xact = (it + 1) < (int)mln8;
        if (xact) {
          const float4* xp = (const float4*)(x + ((size_t)(mst8+it+1u)*512u + mb8)*128u + (size_t)oct*16u);
          float4 a0=xp[0], a1=xp[1], a2=xp[2], a3=xp[3];
          xpre0[0]=f2bf(a0.x); xpre0[1]=f2bf(a0.y); xpre0[2]=f2bf(a0.z); xpre0[3]=f2bf(a0.w);
          xpre0[4]=f2bf(a1.x); xpre0[5]=f2bf(a1.y); xpre0[6]=f2bf(a1.z); xpre0[7]=f2bf(a1.w);
          xpre1[0]=f2bf(a2.x); xpre1[1]=f2bf(a2.y); xpre1[2]=f2bf(a2.z); xpre1[3]=f2bf(a2.w);
          xpre1[4]=f2bf(a3.x); xpre1[5]=f2bf(a3.y); xpre1[6]=f2bf(a3.z); xpre1[7]=f2bf(a3.w);
        } else {
#pragma unroll
          for (int j=0;j<8;++j){ xpre0[j]=0; xpre1[j]=0; }
        }
      }

      __syncthreads();                   // S2: GEMM reads done; A writable

      // ---- LSTM cell (named arrays, constant indices; bias already in acc) ----
      CELL13(acc0, creg0, 0);
      CELL13(acc1, creg1, 1);
      CELL13(acc2, creg2, 2);
      CELL13(acc3, creg3, 3);

      // ---- next-step x into A-tile ----
      *(bf16x8*)(Alds + row8*768 + ((oct*32     ) ^ rsw8)) = xpre0;
      *(bf16x8*)(Alds + row8*768 + ((oct*32 + 16) ^ rsw8)) = xpre1;
    }

    // ---- final hidden store for rows whose segment ran to maxLen ----
    __syncthreads();
    if (maxLen > 0 && mln8 == (uint32_t)maxLen) {
      const size_t grow = (size_t)(mst8 + (uint32_t)(maxLen-1))*512u + mb8;
      short* hp = hidden + grow*256u + (size_t)oct*32u;
#pragma unroll
      for (int q=0;q<4;++q)
        *(bf16x8*)(hp + q*8) = *(const bf16x8*)(Alds + row8*768 + ((256 + oct*64 + q*16) ^ rsw8));
    }
  }
}

// ============================================================================
// K4 (split path): fused heads over dense hidden rows. Unchanged.
// ============================================================================
__global__ __launch_bounds__(512, 1) void k4_heads(
    const short* __restrict__ hidden,
    const short* __restrict__ wa1p, const short* __restrict__ wv1p,
    const short* __restrict__ wa2p, const short* __restrict__ wv2p,
    const float* __restrict__ ba1, const float* __restrict__ bv1,
    const float* __restrict__ ba2, const float* __restrict__ bv2,
    const float* __restrict__ wa3, const float* __restrict__ ba3,
    const float* __restrict__ wv3, const float* __restrict__ bv3,
    const unsigned char* __restrict__ maskB, const uint32_t* __restrict__ maskModePtr,
    float* __restrict__ logits, float* __restrict__ value)
{
  __shared__ char smem[67600];
  char* hidL = smem;                      // [64][512] swizzled
  char* hb1  = smem + 32768;              // [64][256]
  char* hb2  = smem + 49152;              // [64][256]
  float* w3L = (float*)(smem + 65536);    // [4][128]
  float* b3L = (float*)(smem + 67584);

  const int tid  = threadIdx.x;
  const int lane = tid & 63;
  const int wv   = tid >> 6;       // 0..7
  const int gq   = wv & 3;
  const int rh   = wv >> 2;
  const int cl   = lane & 15;
  const int u    = lane >> 4;
  const int ku   = u*16;
  const int swc  = (cl & 7) << 4;
  const int row8 = tid >> 3;       // 0..63
  const int oct  = tid & 7;
  const int rsw8 = (row8 & 7) << 4;
  const size_t r0 = (size_t)blockIdx.x * 64u;

  {
    const short* hp = hidden + (r0 + (size_t)row8)*256u + (size_t)oct*32u;
#pragma unroll
    for (int q=0;q<4;++q)
      *(bf16x8*)(hidL + row8*512 + ((oct*64 + q*16) ^ rsw8)) = *(const bf16x8*)(hp + q*8);
  }
  if (tid < 128) {
    w3L[tid]       = wa3[tid];
    w3L[128 + tid] = wa3[128 + tid];
    w3L[256 + tid] = wa3[256 + tid];
    w3L[384 + tid] = wv3[tid];
  }
  if (tid == 0) { b3L[0]=ba3[0]; b3L[1]=ba3[1]; b3L[2]=ba3[2]; b3L[3]=bv3[0]; }
  const uint32_t maskByteMode = *maskModePtr;
  const int* maskI = (const int*)maskB;
  __syncthreads();

  for (int hd = 0; hd < 2; ++hd) {
    const short* w1p = hd ? wv1p : wa1p;
    const short* w2p = hd ? wv2p : wa2p;
    const float* b1  = hd ? bv1 : ba1;
    const float* b2  = hd ? bv2 : ba2;

    {
      f32x4 h1[2][2];
#pragma unroll
      for (int n1=0;n1<2;++n1){
        f32x4 bv = *(const f32x4*)(b1 + gq*32 + n1*16 + u*4);
        h1[n1][0]=bv; h1[n1][1]=bv;
      }
      for (int kt2=0; kt2<8; ++kt2) {
        bf16x8 bh[2];
#pragma unroll
        for (int r4=0;r4<2;++r4)
          bh[r4] = *(const bf16x8*)(hidL + (rh*32 + r4*16 + cl)*512 + ((kt2*64 + ku) ^ swc));
#pragma unroll
        for (int n1=0;n1<2;++n1) {
          const bf16x8 wf = *(const bf16x8*)(w1p + (size_t)(kt2*8 + gq*2 + n1)*512 + lane*8);
#pragma unroll
          for (int r4=0;r4<2;++r4)
            h1[n1][r4] = __builtin_amdgcn_mfma_f32_16x16x32_bf16(wf, bh[r4], h1[n1][r4], 0,0,0);
        }
      }
#pragma unroll
      for (int n1=0;n1<2;++n1){
#pragma unroll
        for (int r4=0;r4<2;++r4){
          bf16x4 hv;
#pragma unroll
          for (int e=0;e<4;++e) hv[e] = f2bf(ftanh_(h1[n1][r4][e]));
          int row = rh*32 + r4*16 + cl;
          *(bf16x4*)(hb1 + row*256 + ((2*(gq*32 + n1*16 + u*4)) ^ swc)) = hv;
        }
      }
    }
    __syncthreads();                 // hb1 ready

    {
      f32x4 h2[2][2];
#pragma unroll
      for (int n1=0;n1<2;++n1){
        f32x4 bv = *(const f32x4*)(b2 + gq*32 + n1*16 + u*4);
        h2[n1][0]=bv; h2[n1][1]=bv;
      }
      for (int kt2=0; kt2<4; ++kt2) {
        bf16x8 bh[2];
#pragma unroll
        for (int r4=0;r4<2;++r4)
          bh[r4] = *(const bf16x8*)(hb1 + (rh*32 + r4*16 + cl)*256 + ((kt2*64 + ku) ^ swc));
#pragma unroll
        for (int n1=0;n1<2;++n1) {
          const bf16x8 wf = *(const bf16x8*)(w2p + (size_t)(kt2*8 + gq*2 + n1)*512 + lane*8);
#pragma unroll
          for (int r4=0;r4<2;++r4)
            h2[n1][r4] = __builtin_amdgcn_mfma_f32_16x16x32_bf16(wf, bh[r4], h2[n1][r4], 0,0,0);
        }
      }
#pragma unroll
      for (int n1=0;n1<2;++n1){
#pragma unroll
        for (int r4=0;r4<2;++r4){
          bf16x4 hv;
#pragma unroll
          for (int e=0;e<4;++e) hv[e] = f2bf(ftanh_(h2[n1][r4][e]));
          int row = rh*32 + r4*16 + cl;
          *(bf16x4*)(hb2 + row*256 + ((2*(gq*32 + n1*16 + u*4)) ^ swc)) = hv;
        }
      }
    }
    __syncthreads();                 // hb2 ready

    {
      const int row  = tid >> 3;
      const int o    = (tid >> 1) & 3;
      const int half = tid & 1;
      const int sw   = (row&7)<<4;
      float s = half ? 0.0f : b3L[o];
      const float* wr = w3L + o*128 + half*64;
#pragma unroll
      for (int k16=0; k16<8; ++k16) {
        bf16x8 av = *(const bf16x8*)(hb2 + row*256 + (((half*8 + k16)*16) ^ sw));
#pragma unroll
        for (int j=0;j<8;++j) s += bf2f(av[j]) * wr[k16*8+j];
      }
      s += __shfl_xor(s, 1);
      if (half == 0) {
        const size_t grow = r0 + (size_t)row;
        if (hd == 0 && o < 3) {
          const size_t mi = grow*3u + (size_t)o;
          const bool masked = maskByteMode ? (maskB[mi] != 0) : (maskI[mi] != 0);
          logits[mi] = masked ? -1e8f : s;
        } else if (hd == 1 && o == 3) {
          value[grow] = s;
        }
      }
    }
    __syncthreads();                 // hb2/hb1 free for next head
  }
}

// ============================================================================
// K3 fused fallback (v4, proven; v4 weight layout): small-ws path only.
// ============================================================================
__global__ __launch_bounds__(512, 2) void k3_lstm_fused(
    const float* __restrict__ x, const int* __restrict__ done,
    const float* __restrict__ h0, const float* __restrict__ c0,
    const short* __restrict__ wpack, const float* __restrict__ bpack,
    const short* __restrict__ wa1p, const short* __restrict__ wv1p,
    const short* __restrict__ wa2p, const short* __restrict__ wv2p,
    const float* __restrict__ ba1, const float* __restrict__ bv1,
    const float* __restrict__ ba2, const float* __restrict__ bv2,
    const float* __restrict__ wa3, const float* __restrict__ ba3,
    const float* __restrict__ wv3, const float* __restrict__ bv3,
    const unsigned char* __restrict__ maskB,
    const uint32_t* __restrict__ maskModePtr,
    const uint32_t* __restrict__ sortedSegs, const uint32_t* __restrict__ nSegsPtr,
    float* __restrict__ logits, float* __restrict__ value,
    float* __restrict__ hnOut, float* __restrict__ cnOut)
{
  __shared__ char smem[121616];
  char* Alds = smem;
  char* hb1  = smem + 49152;
  char* hb2  = smem + 81920;
  float* biasL = (float*)(smem + 114688);
  uint32_t* meta = (uint32_t*)(smem + 118784);
  float* w3L = (float*)(smem + 119552);
  float* b3L = (float*)(smem + 121600);

  const int tid  = threadIdx.x;
  const int lane = tid & 63;
  const int wv   = tid >> 6;
  const int gq   = wv & 3;
  const int hd   = wv >> 2;
  const int cl   = lane & 15;
  const int u    = lane >> 4;
  const int ku   = u*16;
  const int swc  = (cl & 7) << 4;
  const int rA   = hd*32 + cl;
  const int rB   = rA + 16;
  const int jb   = gq*64 + u*16;
  const int jb2  = 2*jb;

  const int row8 = tid >> 3;
  const int oct  = tid & 7;
  const int rsw8 = (row8 & 7) << 4;

  biasL[tid]       = bpack[tid];
  biasL[512 + tid] = bpack[512 + tid];
  if (tid < 128) {
    w3L[tid]       = wa3[tid];
    w3L[128 + tid] = wa3[128 + tid];
    w3L[256 + tid] = wa3[256 + tid];
    w3L[384 + tid] = wv3[tid];
  }
  if (tid == 0) { b3L[0]=ba3[0]; b3L[1]=ba3[1]; b3L[2]=ba3[2]; b3L[3]=bv3[0]; }

  float4 bH1v[2], bH2v[2];
  {
    const float* b1 = hd ? bv1 : ba1;
    const float* b2 = hd ? bv2 : ba2;
#pragma unroll
    for (int n1=0; n1<2; ++n1) {
      bH1v[n1] = *(const float4*)(b1 + gq*32 + n1*16 + u*4);
      bH2v[n1] = *(const float4*)(b2 + gq*32 + n1*16 + u*4);
    }
  }
  const short* w1p = hd ? wv1p : wa1p;
  const short* w2p = hd ? wv2p : wa2p;

  const uint32_t maskByteMode = *maskModePtr;
  const int* maskI = (const int*)maskB;

  const uint32_t nSegs = *nSegsPtr;
  const uint32_t nGroups = (nSegs + 63u) >> 6;

  for (uint32_t g = blockIdx.x; g < nGroups; g += gridDim.x) {
    __syncthreads();
    if (tid < 64) {
      uint32_t idx = g*64u + (uint32_t)tid;
      uint32_t b=0, st=0, ln=0;
      if (idx < nSegs) {
        uint32_t r = sortedSegs[idx];
        b = r & 511u; st = (r>>9)&1023u; ln = ((r>>19)&1023u) + 1u;
      }
      meta[tid] = b; meta[64+tid] = st; meta[128+tid] = ln;
    }
    __syncthreads();

    const uint32_t mb8  = meta[row8];
    const uint32_t mst8 = meta[64+row8];
    const uint32_t mln8 = meta[128+row8];
    const uint32_t mbA  = meta[rA],    mbB  = meta[rB];
    const uint32_t mstA = meta[64+rA], mstB = meta[64+rB];
    const uint32_t mlnA = meta[128+rA],mlnB = meta[128+rB];
    const int maxLen = (int)meta[128];

    {
      const bool act = (mln8 > 0u);
      float xf[16];
      if (act) {
        const float4* xp = (const float4*)(x + ((size_t)mst8*512u + mb8)*128u + (size_t)oct*16u);
#pragma unroll
        for (int i=0;i<4;++i){ float4 t4 = xp[i]; xf[4*i]=t4.x; xf[4*i+1]=t4.y; xf[4*i+2]=t4.z; xf[4*i+3]=t4.w; }
      } else {
#pragma unroll
        for (int i=0;i<16;++i) xf[i]=0.0f;
      }
      bf16x8 v0, v1;
#pragma unroll
      for (int j=0;j<8;++j){ v0[j]=f2bf(xf[j]); v1[j]=f2bf(xf[8+j]); }
      *(bf16x8*)(Alds + row8*768 + ((oct*32     ) ^ rsw8)) = v0;
      *(bf16x8*)(Alds + row8*768 + ((oct*32 + 16) ^ rsw8)) = v1;

      const bool useInit = act && (mst8 == 0u) && (done[mb8] == 0);
      float hf[32];
      if (useInit) {
        const float4* hp = (const float4*)(h0 + (size_t)mb8*256u + (size_t)oct*32u);
#pragma unroll
        for (int i=0;i<8;++i){ float4 t4 = hp[i]; hf[4*i]=t4.x; hf[4*i+1]=t4.y; hf[4*i+2]=t4.z; hf[4*i+3]=t4.w; }
      } else {
#pragma unroll
        for (int i=0;i<32;++i) hf[i]=0.0f;
      }
#pragma unroll
      for (int q=0;q<4;++q){
        bf16x8 hv;
#pragma unroll
        for (int j=0;j<8;++j) hv[j]=f2bf(hf[q*8+j]);
        *(bf16x8*)(Alds + row8*768 + ((256 + oct*64 + q*16) ^ rsw8)) = hv;
      }
    }

    float cregA[16], cregB[16];
    {
      const bool initA = (mlnA > 0u) && (mstA == 0u) && (done[mbA] == 0);
      const bool initB = (mlnB > 0u) && (mstB == 0u) && (done[mbB] == 0);
      f32x4 ca[4], cb[4];
#pragma unroll
      for (int q=0;q<4;++q){
        ca[q] = initA ? *(const f32x4*)(c0 + (size_t)mbA*256u + jb + q*4) : (f32x4){0.f,0.f,0.f,0.f};
        cb[q] = initB ? *(const f32x4*)(c0 + (size_t)mbB*256u + jb + q*4) : (f32x4){0.f,0.f,0.f,0.f};
      }
#pragma unroll
      for (int nt=0;nt<16;++nt){ cregA[nt]=ca[nt>>2][nt&3]; cregB[nt]=cb[nt>>2][nt&3]; }
    }

    for (int it = 0; it < maxLen; ++it) {
      __syncthreads();

      f32x4 accA[16], accB[16];
#pragma unroll
      for (int nt=0;nt<16;++nt){
        f32x4 bv = *(const f32x4*)(biasL + gq*256 + nt*16 + u*4);
        accA[nt]=bv; accB[nt]=bv;
      }
      for (int kt=0; kt<12; ++kt) {
        if ((kt & 3) == 0) __builtin_amdgcn_s_barrier();
        const short* wkt = wpack + (size_t)(kt*4 + gq)*8192 + lane*8;
        bf16x8 bfA = *(const bf16x8*)(Alds + rA*768 + ((kt*64 + ku) ^ swc));
        bf16x8 bfB = *(const bf16x8*)(Alds + rB*768 + ((kt*64 + ku) ^ swc));
#pragma unroll
        for (int nt=0;nt<16;++nt) {
          const bf16x8 wf = *(const bf16x8*)(wkt + nt*512);
          accA[nt] = __builtin_amdgcn_mfma_f32_16x16x32_bf16(wf, bfA, accA[nt], 0,0,0);
          accB[nt] = __builtin_amdgcn_mfma_f32_16x16x32_bf16(wf, bfB, accB[nt], 0,0,0);
        }
      }

      float4 xq0,xq1,xq2,xq3;
      {
        const bool xact = (it + 1) < (int)mln8;
        if (xact) {
          const float4* xp = (const float4*)(x + ((size_t)(mst8+it+1u)*512u + mb8)*128u + (size_t)oct*16u);
          xq0=xp[0]; xq1=xp[1]; xq2=xp[2]; xq3=xp[3];
        } else {
          xq0=xq1=xq2=xq3=make_float4(0.f,0.f,0.f,0.f);
        }
      }

      __syncthreads();

      float hfA[16], hfB[16];
#pragma unroll
      for (int nt=0;nt<16;++nt) {
        f32x4 gA = accA[nt];
        float i0=fsig(gA[0]), f0=fsig(gA[1]), g0=ftanh_(gA[2]), o0=fsig(gA[3]);
        float cA = f0*cregA[nt] + i0*g0; cregA[nt]=cA; hfA[nt] = o0*ftanh_(cA);
        f32x4 gB = accB[nt];
        float i1=fsig(gB[0]), f1=fsig(gB[1]), g1=ftanh_(gB[2]), o1=fsig(gB[3]);
        float cB = f1*cregB[nt] + i1*g1; cregB[nt]=cB; hfB[nt] = o1*ftanh_(cB);
      }
      {
        bf16x8 hv0, hv1;
#pragma unroll
        for (int q=0;q<8;++q){ hv0[q]=f2bf(hfA[q]); hv1[q]=f2bf(hfA[8+q]); }
        *(bf16x8*)(Alds + rA*768 + ((256 + jb2     ) ^ swc)) = hv0;
        *(bf16x8*)(Alds + rA*768 + ((256 + jb2 + 16) ^ swc)) = hv1;
#pragma unroll
        for (int q=0;q<8;++q){ hv0[q]=f2bf(hfB[q]); hv1[q]=f2bf(hfB[8+q]); }
        *(bf16x8*)(Alds + rB*768 + ((256 + jb2     ) ^ swc)) = hv0;
        *(bf16x8*)(Alds + rB*768 + ((256 + jb2 + 16) ^ swc)) = hv1;
      }
      if ((it == (int)mlnA - 1) && (mstA + mlnA == 1024u)) {
        float4* hp4 = (float4*)(hnOut + (size_t)mbA*256u + jb);
        float4* cp4 = (float4*)(cnOut + (size_t)mbA*256u + jb);
#pragma unroll
        for (int q=0;q<4;++q){
          hp4[q] = make_float4(hfA[4*q],hfA[4*q+1],hfA[4*q+2],hfA[4*q+3]);
          cp4[q] = make_float4(cregA[4*q],cregA[4*q+1],cregA[4*q+2],cregA[4*q+3]);
        }
      }
      if ((it == (int)mlnB - 1) && (mstB + mlnB == 1024u)) {
        float4* hp4 = (float4*)(hnOut + (size_t)mbB*256u + jb);
        float4* cp4 = (float4*)(cnOut + (size_t)mbB*256u + jb);
#pragma unroll
        for (int q=0;q<4;++q){
          hp4[q] = make_float4(hfB[4*q],hfB[4*q+1],hfB[4*q+2],hfB[4*q+3]);
          cp4[q] = make_float4(cregB[4*q],cregB[4*q+1],cregB[4*q+2],cregB[4*q+3]);
        }
      }
      {
        float xf[16];
        xf[0]=xq0.x; xf[1]=xq0.y; xf[2]=xq0.z; xf[3]=xq0.w;
        xf[4]=xq1.x; xf[5]=xq1.y; xf[6]=xq1.z; xf[7]=xq1.w;
        xf[8]=xq2.x; xf[9]=xq2.y; xf[10]=xq2.z; xf[11]=xq2.w;
        xf[12]=xq3.x; xf[13]=xq3.y; xf[14]=xq3.z; xf[15]=xq3.w;
        bf16x8 v0, v1;
#pragma unroll
        for (int j=0;j<8;++j){ v0[j]=f2bf(xf[j]); v1[j]=f2bf(xf[8+j]); }
        *(bf16x8*)(Alds + row8*768 + ((oct*32     ) ^ rsw8)) = v0;
        *(bf16x8*)(Alds + row8*768 + ((oct*32 + 16) ^ rsw8)) = v1;
      }

      __syncthreads();

      {
        f32x4 h1[2][4];
#pragma unroll
        for (int n1=0;n1<2;++n1){
          f32x4 bv = {bH1v[n1].x, bH1v[n1].y, bH1v[n1].z, bH1v[n1].w};
#pragma unroll
          for (int r4=0;r4<4;++r4) h1[n1][r4] = bv;
        }
        for (int kt2=0; kt2<8; ++kt2) {
          bf16x8 bh[4];
#pragma unroll
          for (int r4=0;r4<4;++r4)
            bh[r4] = *(const bf16x8*)(Alds + (r4*16+cl)*768 + ((256 + kt2*64 + ku) ^ swc));
#pragma unroll
          for (int n1=0;n1<2;++n1) {
            const bf16x8 wf = *(const bf16x8*)(w1p + (size_t)(kt2*8 + gq*2 + n1)*512 + lane*8);
#pragma unroll
            for (int r4=0;r4<4;++r4)
              h1[n1][r4] = __builtin_amdgcn_mfma_f32_16x16x32_bf16(wf, bh[r4], h1[n1][r4], 0,0,0);
          }
        }
#pragma unroll
        for (int n1=0;n1<2;++n1){
#pragma unroll
          for (int r4=0;r4<4;++r4){
            bf16x4 hv;
#pragma unroll
            for (int e=0;e<4;++e) hv[e] = f2bf(ftanh_(h1[n1][r4][e]));
            int row = r4*16 + cl;
            *(bf16x4*)(hb1 + hd*16384 + row*256 + ((2*(gq*32 + n1*16 + u*4)) ^ swc)) = hv;
          }
        }
      }
      __syncthreads();

      {
        f32x4 h2[2][4];
#pragma unroll
        for (int n1=0;n1<2;++n1){
          f32x4 bv = {bH2v[n1].x, bH2v[n1].y, bH2v[n1].z, bH2v[n1].w};
#pragma unroll
          for (int r4=0;r4<4;++r4) h2[n1][r4] = bv;
        }
        const char* hbIn = hb1 + hd*16384;
        for (int kt2=0; kt2<4; ++kt2) {
          bf16x8 bh[4];
#pragma unroll
          for (int r4=0;r4<4;++r4)
            bh[r4] = *(const bf16x8*)(hbIn + (r4*16+cl)*256 + ((kt2*64 + ku) ^ swc));
#pragma unroll
          for (int n1=0;n1<2;++n1) {
            const bf16x8 wf = *(const bf16x8*)(w2p + (size_t)(kt2*8 + gq*2 + n1)*512 + lane*8);
#pragma unroll
            for (int r4=0;r4<4;++r4)
              h2[n1][r4] = __builtin_amdgcn_mfma_f32_16x16x32_bf16(wf, bh[r4], h2[n1][r4], 0,0,0);
          }
        }
#pragma unroll
        for (int n1=0;n1<2;++n1){
#pragma unroll
          for (int r4=0;r4<4;++r4){
            bf16x4 hv;
#pragma unroll
            for (int e=0;e<4;++e) hv[e] = f2bf(ftanh_(h2[n1][r4][e]));
            int row = r4*16 + cl;
            *(bf16x4*)(hb2 + hd*16384 + row*256 + ((2*(gq*32 + n1*16 + u*4)) ^ swc)) = hv;
          }
        }
      }
      __syncthreads();

      {
        const int frow = tid >> 3;
        const int o    = (tid >> 1) & 3;
        const int half = tid & 1;
        const uint32_t fmb  = meta[frow];
        const uint32_t fmst = meta[64+frow];
        const uint32_t fmln = meta[128+frow];
        const char* srcb = (o < 3) ? hb2 : (hb2 + 16384);
        const int sw = (frow&7)<<4;
        float s = half ? 0.0f : b3L[o];
        const float* wr = w3L + o*128 + half*64;
#pragma unroll
        for (int k16=0; k16<8; ++k16) {
          bf16x8 av = *(const bf16x8*)(srcb + frow*256 + (((half*8 + k16)*16) ^ sw));
#pragma unroll
          for (int j=0;j<8;++j) s += bf2f(av[j]) * wr[k16*8+j];
        }
        s += __shfl_xor(s, 1);
        if (half == 0 && it < (int)fmln) {
          const size_t grow = (size_t)((int)fmst + it)*512u + fmb;
          if (o < 3) {
            const size_t mi = grow*3u + (size_t)o;
            const bool masked = maskByteMode ? (maskB[mi] != 0) : (maskI[mi] != 0);
            logits[mi] = masked ? -1e8f : s;
          } else {
            value[grow] = s;
          }
        }
      }
    }
  }
}

// ============================================================================
extern "C" void kernel_launch(void* const* d_in, const int* in_sizes, int n_in,
                              void* d_out, int out_size, void* d_ws, size_t ws_size,
                              hipStream_t stream) {
  const float* x    = (const float*)d_in[0];
  const int*   done = (const int*)d_in[1];
  const unsigned char* mask = (const unsigned char*)d_in[2];
  const float* h0   = (const float*)d_in[3];
  const float* c0   = (const float*)d_in[4];
  const float* wih  = (const float*)d_in[5];
  const float* whh  = (const float*)d_in[6];
  const float* bih  = (const float*)d_in[7];
  const float* bhh  = (const float*)d_in[8];
  const float* wa1  = (const float*)d_in[9];
  const float* ba1  = (const float*)d_in[10];
  const float* wa2  = (const float*)d_in[11];
  const float* ba2  = (const float*)d_in[12];
  const float* wa3  = (const float*)d_in[13];
  const float* ba3  = (const float*)d_in[14];
  const float* wv1  = (const float*)d_in[15];
  const float* bv1  = (const float*)d_in[16];
  const float* wv2  = (const float*)d_in[17];
  const float* bv2  = (const float*)d_in[18];
  const float* wv3  = (const float*)d_in[19];
  const float* bv3  = (const float*)d_in[20];

  char* ws = (char*)d_ws;
  float* outLogits = (float*)d_out;                 // 524288*3
  float* outValue  = outLogits + 1572864;           // 524288
  float* outHn     = outValue  + 524288;            // 131072
  float* outCn     = outHn     + 131072;            // 131072

  hipMemsetAsync(ws + WS_META, 0, 16384, stream);

  k0b_packheads<<<24, 512, 0, stream>>>(wa1, wv1, wa2, wv2,
      (short*)(ws + WS_WA1P), (short*)(ws + WS_WV1P),
      (short*)(ws + WS_WA2P), (short*)(ws + WS_WV2P));

  k1_maskmode<<<64, 256, 0, stream>>>(mask, (uint32_t*)(ws + WS_META + 16));

  k2a_segments<<<512, 256, 0, stream>>>(done, (uint32_t*)(ws + WS_SEGS),
                                        (uint32_t*)(ws + WS_META));
  k2b_hist<<<128, 512, 0, stream>>>((const uint32_t*)(ws + WS_SEGS),
      (const uint32_t*)(ws + WS_META), (uint32_t*)(ws + WS_META + 4096));
  k2c_scan<<<1, 1024, 0, stream>>>((const uint32_t*)(ws + WS_META + 4096),
      (uint32_t*)(ws + WS_META + 12288));
  k2d_scatter<<<128, 512, 0, stream>>>((const uint32_t*)(ws + WS_SEGS),
      (const uint32_t*)(ws + WS_META), (uint32_t*)(ws + WS_META + 12288),
      (uint32_t*)(ws + WS_SORTED));

  if (ws_size >= WS_NEED_SPLIT) {
    k0a_packmain<<<96, 512, 0, stream>>>(wih, whh, bih, bhh,
        (short*)(ws + WS_WMAIN), (float*)(ws + WS_BMAIN));
    k3r_lstm<<<256, 512, 0, stream>>>(x, done, h0, c0,
        (const short*)(ws + WS_WMAIN), (const float*)(ws + WS_BMAIN),
        (const uint32_t*)(ws + WS_SORTED), (const uint32_t*)(ws + WS_META),
        (short*)(ws + WS_HID), outHn, outCn);
    k4_heads<<<8192, 512, 0, stream>>>((const short*)(ws + WS_HID),
        (const short*)(ws + WS_WA1P), (const short*)(ws + WS_WV1P),
        (const short*)(ws + WS_WA2P), (const short*)(ws + WS_WV2P),
        ba1, bv1, ba2, bv2, wa3, ba3, wv3, bv3,
        mask, (const uint32_t*)(ws + WS_META + 16),
        outLogits, outValue);
  } else {
    k0a_packmain_v4<<<96, 512, 0, stream>>>(wih, whh, bih, bhh,
        (short*)(ws + WS_WMAIN), (float*)(ws + WS_BMAIN));
    k3_lstm_fused<<<256, 512, 0, stream>>>(x, done, h0, c0,
        (const short*)(ws + WS_WMAIN), (const float*)(ws + WS_BMAIN),
        (const short*)(ws + WS_WA1P), (const short*)(ws + WS_WV1P),
        (const short*)(ws + WS_WA2P), (const short*)(ws + WS_WV2P),
        ba1, bv1, ba2, bv2, wa3, ba3, wv3, bv3,
        mask, (const uint32_t*)(ws + WS_META + 16),
        (const uint32_t*)(ws + WS_SORTED), (const uint32_t*)(ws + WS_META),
        outLogits, outValue, outHn, outCn);
  }

  (void)in_sizes; (void)n_in; (void)out_size;
}

// Round 14
// 1396.670 us; speedup vs baseline: 2.6467x; 2.6467x over previous
//
#include <hip/hip_runtime.h>
#include <hip/hip_bf16.h>
#include <stdint.h>
#include <stddef.h>

// ============================================================================
// PPOAgent fused pipeline for MI355X (gfx950) — v14 == byte-exact v7 (proven
// 1397us total; k3r 1140us, zero spill). v8-v13 post-mortems: every attempt
// to pipeline or restructure k3r's weight loads (DMA staging, reg dbuf x3,
// 8-gq geometry x3) tipped the 256-reg/wave cliff -> 3.5GB scratch spill.
// v7 sits exactly at the cliff with zero slack; it is the design-family
// optimum. k3r FROZEN per R11/R12 pre-commit.
// ============================================================================

typedef short bf16x8 __attribute__((ext_vector_type(8)));
typedef short bf16x4 __attribute__((ext_vector_type(4)));
typedef float f32x4  __attribute__((ext_vector_type(4)));

#define LOG2E 1.44269504088896340736f

__device__ __forceinline__ float fexp2(float x){ return __builtin_amdgcn_exp2f(x); }
__device__ __forceinline__ float frcpf_(float x){ return __builtin_amdgcn_rcpf(x); }
__device__ __forceinline__ float fsig(float x){ return frcpf_(1.0f + fexp2(-x*LOG2E)); }
__device__ __forceinline__ float ftanh_(float x){ return 1.0f - 2.0f*frcpf_(1.0f + fexp2(x*(2.0f*LOG2E))); }

__device__ __forceinline__ short f2bf(float f){
  unsigned u = __builtin_bit_cast(unsigned, f);
  u += 0x7fffu + ((u>>16)&1u);
  return (short)(u>>16);
}
__device__ __forceinline__ float bf2f(short h){
  unsigned u = ((unsigned)(unsigned short)h)<<16;
  return __builtin_bit_cast(float, u);
}

// ---------------- workspace layout (bytes) ----------------
static constexpr size_t WS_WMAIN  = 0;          // packed [Wih;Whh] A-frag stream, 768KB
static constexpr size_t WS_WA1P   = 786432;
static constexpr size_t WS_WV1P   = 851968;
static constexpr size_t WS_WA2P   = 917504;
static constexpr size_t WS_WV2P   = 950272;
static constexpr size_t WS_BMAIN  = 983040;     // 1024 f32 packed-order bias
static constexpr size_t WS_META   = 1048576;    // nSegs@+0 ; maskMode@+16 ; hist@+4096 ; curs@+12288
static constexpr size_t WS_SEGS   = 1081344;    // 524288 u32
static constexpr size_t WS_SORTED = 3178496;    // 524288 u32  (end 5275648)
static constexpr size_t WS_HID    = 5275648;    // 524288 x 256 bf16 = 268435456
static constexpr size_t WS_NEED_SPLIT = WS_HID + 268435456; // 273711104

// ============================================================================
// K0a: pack [W_ih; W_hh] as MFMA A-fragment stream + packed-order bias.
// cgp = gq*256 + nt*16 + u*4 + e : j = gq*64+u*16+nt, gate e, g = e*256+j.
// Chunk (kt,gq): addr(short) = (kt*4+gq)*8192 + nt*512 + lane*8
// ============================================================================
__global__ void k0a_packmain(const float* __restrict__ wih, const float* __restrict__ whh,
                             const float* __restrict__ bih, const float* __restrict__ bhh,
                             short* __restrict__ wp, float* __restrict__ bp)
{
  int tidg = blockIdx.x*512 + threadIdx.x;     // 0..49151
  {
    int lane = tidg & 63;
    int nt   = (tidg>>6) & 15;
    int ci   = tidg>>10;                       // 0..47
    int kt = ci>>2, gq = ci&3;
    int gs = lane & 15;
    int ug = gs>>2, eg = gs&3;
    int j  = gq*64 + ug*16 + nt;
    int g  = eg*256 + j;
    int k0 = kt*32 + (lane>>4)*8;
    bf16x8 ov;
#pragma unroll
    for (int jj=0;jj<8;++jj){
      int k = k0 + jj;
      float v = (k < 128) ? wih[(size_t)g*128 + k] : whh[(size_t)g*256 + (k-128)];
      ov[jj] = f2bf(v);
    }
    *(bf16x8*)(wp + (size_t)tidg*8) = ov;
  }
  if (tidg < 1024) {
    int cgp = tidg;
    int gq = cgp>>8, nt = (cgp>>4)&15, ug = (cgp>>2)&3, eg = cgp&3;
    int g = eg*256 + gq*64 + ug*16 + nt;
    bp[cgp] = bih[g] + bhh[g];
  }
}

// K0b: pack head weights (N x K row-major -> frag stream)
__global__ void k0b_packheads(const float* __restrict__ wa1, const float* __restrict__ wv1,
                              const float* __restrict__ wa2, const float* __restrict__ wv2,
                              short* __restrict__ wa1p, short* __restrict__ wv1p,
                              short* __restrict__ wa2p, short* __restrict__ wv2p)
{
  int p = blockIdx.x*512 + threadIdx.x;     // 0..12287
  const float* src; short* dst; int K; int pl;
  if (p < 4096)       { src=wa1; dst=wa1p; K=256; pl=p; }
  else if (p < 8192)  { src=wv1; dst=wv1p; K=256; pl=p-4096; }
  else if (p < 10240) { src=wa2; dst=wa2p; K=128; pl=p-8192; }
  else                { src=wv2; dst=wv2p; K=128; pl=p-10240; }
  int lane = pl & 63;
  int f    = pl >> 6;
  int nt   = f & 7;
  int kt   = f >> 3;
  int n  = nt*16 + (lane&15);
  int k0 = kt*32 + (lane>>4)*8;
  bf16x8 ov;
#pragma unroll
  for (int j=0;j<8;++j) ov[j] = f2bf(src[(size_t)n*K + k0 + j]);
  *(bf16x8*)(dst + (size_t)pl*8) = ov;
}

// K1: detect mask storage layout (byte-bools vs int32).
__global__ void k1_maskmode(const unsigned char* __restrict__ mask, uint32_t* __restrict__ flag)
{
  int i = blockIdx.x*256 + threadIdx.x;
  uint32_t v = ((i & 3) != 0) ? (uint32_t)mask[i] : 0u;
  if (v) atomicOr((unsigned int*)flag, 1u);
}

// ============================================================================
// K2a: per batch column, find segment starts. record = (len-1)<<19|start<<9|b
// ============================================================================
__global__ void k2a_segments(const int* __restrict__ done, uint32_t* __restrict__ segs,
                             uint32_t* __restrict__ nSegs)
{
  const int b = blockIdx.x;
  const int tid = threadIdx.x;
  __shared__ uint16_t starts[1025];
  __shared__ uint32_t cnts[256];
  __shared__ uint32_t basePos;

  uint32_t my[4]; int myn = 0;
  int t0 = tid*4;
#pragma unroll
  for (int i=0;i<4;++i){
    int t = t0 + i;
    int d = done[(size_t)t*512 + b];
    if (t == 0 || d != 0) my[myn++] = (uint32_t)t;
  }
  cnts[tid] = (uint32_t)myn;
  __syncthreads();
  for (int off=1; off<256; off<<=1){
    uint32_t v = (tid >= off) ? cnts[tid-off] : 0u;
    __syncthreads();
    cnts[tid] += v;
    __syncthreads();
  }
  uint32_t myBase = cnts[tid] - (uint32_t)myn;
  uint32_t ns = cnts[255];
  for (int i=0;i<myn;++i) starts[myBase+i] = (uint16_t)my[i];
  if (tid == 0) {
    starts[ns] = 1024;
    basePos = atomicAdd((unsigned int*)nSegs, ns);
  }
  __syncthreads();
  for (uint32_t i = tid; i < ns; i += 256) {
    uint32_t st = starts[i];
    uint32_t ln = (uint32_t)starts[i+1] - st;
    segs[basePos + i] = ((ln-1u)<<19) | (st<<9) | (uint32_t)b;
  }
}

// K2b: LDS histogram, ~30 global atomics per block.
__global__ void k2b_hist(const uint32_t* __restrict__ segs, const uint32_t* __restrict__ nSegs,
                         uint32_t* __restrict__ hist)
{
  __shared__ uint32_t lh[1025];
  const uint32_t n = *nSegs;
  for (int i = threadIdx.x; i < 1025; i += 512) lh[i] = 0;
  __syncthreads();
  for (uint32_t i = blockIdx.x*512u + threadIdx.x; i < n; i += gridDim.x*512u) {
    uint32_t ln = ((segs[i]>>19)&1023u) + 1u;
    atomicAdd(&lh[ln], 1u);
  }
  __syncthreads();
  for (int i = threadIdx.x; i < 1025; i += 512)
    if (lh[i]) atomicAdd((unsigned int*)&hist[i], lh[i]);
}

// K2c: bucketStart[len] = #segments with length > len (descending sort)
__global__ void k2c_scan(const uint32_t* __restrict__ hist, uint32_t* __restrict__ curs)
{
  __shared__ uint32_t s[1024];
  const int tid = threadIdx.x;
  uint32_t own = hist[tid+1];
  s[tid] = own;
  __syncthreads();
  for (int off=1; off<1024; off<<=1){
    uint32_t v = (tid+off < 1024) ? s[tid+off] : 0u;
    __syncthreads();
    s[tid] += v;
    __syncthreads();
  }
  curs[tid+1] = s[tid] - own;
  if (tid == 0) curs[0] = 0;
}

// K2d: per-block count -> one global atomic per (block,bin) -> local place.
__global__ void k2d_scatter(const uint32_t* __restrict__ segs, const uint32_t* __restrict__ nSegs,
                            uint32_t* __restrict__ curs, uint32_t* __restrict__ sorted)
{
  __shared__ uint32_t lh[1025];
  __shared__ uint32_t base[1025];
  const uint32_t n = *nSegs;
  const uint32_t chunk = (n + 127u) >> 7;          // gridDim.x == 128
  const uint32_t lo = blockIdx.x * chunk;
  const uint32_t hi = (lo + chunk < n) ? (lo + chunk) : n;
  for (int i = threadIdx.x; i < 1025; i += 512) lh[i] = 0;
  __syncthreads();
  for (uint32_t i = lo + threadIdx.x; i < hi; i += 512u) {
    uint32_t ln = ((segs[i]>>19)&1023u) + 1u;
    atomicAdd(&lh[ln], 1u);
  }
  __syncthreads();
  for (int i = threadIdx.x; i < 1025; i += 512) {
    uint32_t c = lh[i];
    if (c) base[i] = atomicAdd((unsigned int*)&curs[i], c);
    lh[i] = 0;
  }
  __syncthreads();
  for (uint32_t i = lo + threadIdx.x; i < hi; i += 512u) {
    uint32_t r = segs[i];
    uint32_t ln = ((r>>19)&1023u) + 1u;
    uint32_t pos = base[ln] + atomicAdd(&lh[ln], 1u);
    sorted[pos] = r;
  }
}

// ============================================================================
// K3r (v7, FROZEN): recurrence only. 512 thr = 8 waves = (gq 0..3)x(rh 0..1).
// Wave: gates gq*256..+256 x rows rh*32..+32 (rA=rh*32+cl, rB=rA+16), acc 2x16.
// A-tile [64][768B] swz ^(row&7)<<4. 2 barriers/iter + convergence s_barrier.
// 128 AGPR acc + <=128 arch regs (bf16 h/x packing, scalar rare hn/cn stores).
// ============================================================================
__global__ __launch_bounds__(512, 2) void k3r_lstm(
    const float* __restrict__ x, const int* __restrict__ done,
    const float* __restrict__ h0, const float* __restrict__ c0,
    const short* __restrict__ wpack, const float* __restrict__ bpack,
    const uint32_t* __restrict__ sortedSegs, const uint32_t* __restrict__ nSegsPtr,
    short* __restrict__ hidden, float* __restrict__ hnOut, float* __restrict__ cnOut)
{
  __shared__ char smem[54016];
  char* Alds = smem;                            // [64][768] swizzled
  float* biasL = (float*)(smem + 49152);        // 1024 f32
  uint32_t* meta = (uint32_t*)(smem + 53248);   // b[64], st@+64, len@+128

  const int tid  = threadIdx.x;
  const int lane = tid & 63;
  const int wv   = tid >> 6;        // 0..7
  const int gq   = wv & 3;
  const int rh   = wv >> 2;
  const int cl   = lane & 15;
  const int u    = lane >> 4;
  const int ku   = u*16;
  const int swc  = (cl & 7) << 4;
  const int rA   = rh*32 + cl;
  const int rB   = rA + 16;
  const int jb   = gq*64 + u*16;
  const int jb2  = 2*jb;

  const int row8 = tid >> 3;        // 0..63
  const int oct  = tid & 7;
  const int rsw8 = (row8 & 7) << 4;

  biasL[tid]       = bpack[tid];
  biasL[512 + tid] = bpack[512 + tid];

  const uint32_t nSegs = *nSegsPtr;
  const uint32_t nGroups = (nSegs + 63u) >> 6;

  for (uint32_t g = blockIdx.x; g < nGroups; g += gridDim.x) {
    __syncthreads();                       // prev group fully consumed
    if (tid < 64) {
      uint32_t idx = g*64u + (uint32_t)tid;
      uint32_t b=0, st=0, ln=0;
      if (idx < nSegs) {
        uint32_t r = sortedSegs[idx];
        b = r & 511u; st = (r>>9)&1023u; ln = ((r>>19)&1023u) + 1u;
      }
      meta[tid] = b; meta[64+tid] = st; meta[128+tid] = ln;
    }
    __syncthreads();

    const uint32_t mb8  = meta[row8];
    const uint32_t mst8 = meta[64+row8];
    const uint32_t mln8 = meta[128+row8];
    const uint32_t mbA  = meta[rA],    mbB  = meta[rB];
    const uint32_t mstA = meta[64+rA], mstB = meta[64+rB];
    const uint32_t mlnA = meta[128+rA],mlnB = meta[128+rB];
    const int maxLen = (int)meta[128];   // desc sort -> slot 0 max

    // ---- group init: x(iter0) [0,256) + FULL h [256,768) ----
    {
      const bool act = (mln8 > 0u);
      float xf[16];
      if (act) {
        const float4* xp = (const float4*)(x + ((size_t)mst8*512u + mb8)*128u + (size_t)oct*16u);
#pragma unroll
        for (int i=0;i<4;++i){ float4 t4 = xp[i]; xf[4*i]=t4.x; xf[4*i+1]=t4.y; xf[4*i+2]=t4.z; xf[4*i+3]=t4.w; }
      } else {
#pragma unroll
        for (int i=0;i<16;++i) xf[i]=0.0f;
      }
      bf16x8 v0, v1;
#pragma unroll
      for (int j=0;j<8;++j){ v0[j]=f2bf(xf[j]); v1[j]=f2bf(xf[8+j]); }
      *(bf16x8*)(Alds + row8*768 + ((oct*32     ) ^ rsw8)) = v0;
      *(bf16x8*)(Alds + row8*768 + ((oct*32 + 16) ^ rsw8)) = v1;

      const bool useInit = act && (mst8 == 0u) && (done[mb8] == 0);
      float hf[32];
      if (useInit) {
        const float4* hp = (const float4*)(h0 + (size_t)mb8*256u + (size_t)oct*32u);
#pragma unroll
        for (int i=0;i<8;++i){ float4 t4 = hp[i]; hf[4*i]=t4.x; hf[4*i+1]=t4.y; hf[4*i+2]=t4.z; hf[4*i+3]=t4.w; }
      } else {
#pragma unroll
        for (int i=0;i<32;++i) hf[i]=0.0f;
      }
#pragma unroll
      for (int q=0;q<4;++q){
        bf16x8 hv;
#pragma unroll
        for (int j=0;j<8;++j) hv[j]=f2bf(hf[q*8+j]);
        *(bf16x8*)(Alds + row8*768 + ((256 + oct*64 + q*16) ^ rsw8)) = hv;
      }
    }

    // ---- c state init (per-lane rows rA/rB, j = jb + nt) ----
    float cregA[16], cregB[16];
    {
      const bool initA = (mlnA > 0u) && (mstA == 0u) && (done[mbA] == 0);
      const bool initB = (mlnB > 0u) && (mstB == 0u) && (done[mbB] == 0);
      f32x4 ca[4], cb[4];
#pragma unroll
      for (int q=0;q<4;++q){
        ca[q] = initA ? *(const f32x4*)(c0 + (size_t)mbA*256u + jb + q*4) : (f32x4){0.f,0.f,0.f,0.f};
        cb[q] = initB ? *(const f32x4*)(c0 + (size_t)mbB*256u + jb + q*4) : (f32x4){0.f,0.f,0.f,0.f};
      }
#pragma unroll
      for (int nt=0;nt<16;++nt){ cregA[nt]=ca[nt>>2][nt&3]; cregB[nt]=cb[nt>>2][nt&3]; }
    }

    for (int it = 0; it < maxLen; ++it) {
      __syncthreads();                   // S1: A-tile (x_t, h_{t-1}) ready

      // ---- deferred hidden store of h_{t-1} (coalesced, read-only vs GEMM) ----
      if (it >= 1 && (uint32_t)(it-1) < mln8) {
        const size_t grow = (size_t)(mst8 + (uint32_t)(it-1))*512u + mb8;
        short* hp = hidden + grow*256u + (size_t)oct*32u;
#pragma unroll
        for (int q=0;q<4;++q)
          *(bf16x8*)(hp + q*8) = *(const bf16x8*)(Alds + row8*768 + ((256 + oct*64 + q*16) ^ rsw8));
      }

      // ---- GEMM: C[gates][rows] = Wp @ [x|h]^T + bias ----
      f32x4 accA[16], accB[16];
#pragma unroll
      for (int nt=0;nt<16;++nt){
        f32x4 bv = *(const f32x4*)(biasL + gq*256 + nt*16 + u*4);
        accA[nt]=bv; accB[nt]=bv;
      }
      for (int kt=0; kt<12; ++kt) {
        if ((kt & 3) == 0) __builtin_amdgcn_s_barrier();   // rh-pair convergence (L1 chunk reuse)
        const short* wkt = wpack + (size_t)(kt*4 + gq)*8192 + lane*8;
        bf16x8 bfA = *(const bf16x8*)(Alds + rA*768 + ((kt*64 + ku) ^ swc));
        bf16x8 bfB = *(const bf16x8*)(Alds + rB*768 + ((kt*64 + ku) ^ swc));
#pragma unroll
        for (int nt=0;nt<16;++nt) {
          const bf16x8 wf = *(const bf16x8*)(wkt + nt*512);
          accA[nt] = __builtin_amdgcn_mfma_f32_16x16x32_bf16(wf, bfA, accA[nt], 0,0,0);
          accB[nt] = __builtin_amdgcn_mfma_f32_16x16x32_bf16(wf, bfB, accB[nt], 0,0,0);
        }
      }

      // ---- x prefetch for it+1 (convert to bf16 immediately: 8 regs) ----
      bf16x8 xpre0, xpre1;
      {
        const bool xact = (it + 1) < (int)mln8;
        if (xact) {
          const float4* xp = (const float4*)(x + ((size_t)(mst8+it+1u)*512u + mb8)*128u + (size_t)oct*16u);
          float4 a0=xp[0], a1=xp[1], a2=xp[2], a3=xp[3];
          xpre0[0]=f2bf(a0.x); xpre0[1]=f2bf(a0.y); xpre0[2]=f2bf(a0.z); xpre0[3]=f2bf(a0.w);
          xpre0[4]=f2bf(a1.x); xpre0[5]=f2bf(a1.y); xpre0[6]=f2bf(a1.z); xpre0[7]=f2bf(a1.w);
          xpre1[0]=f2bf(a2.x); xpre1[1]=f2bf(a2.y); xpre1[2]=f2bf(a2.z); xpre1[3]=f2bf(a2.w);
          xpre1[4]=f2bf(a3.x); xpre1[5]=f2bf(a3.y); xpre1[6]=f2bf(a3.z); xpre1[7]=f2bf(a3.w);
        } else {
#pragma unroll
          for (int j=0;j<8;++j){ xpre0[j]=0; xpre1[j]=0; }
        }
      }

      __syncthreads();                   // S2: GEMM reads done; A writable

      // ---- LSTM cell: per-lane regs, h packed to bf16 inline ----
      const bool finA = (it == (int)mlnA - 1) && (mstA + mlnA == 1024u) && (mlnA > 0u);
      const bool finB = (it == (int)mlnB - 1) && (mstB + mlnB == 1024u) && (mlnB > 0u);
      bf16x8 hvA0, hvA1, hvB0, hvB1;
#pragma unroll
      for (int nt=0;nt<16;++nt) {
        f32x4 gA = accA[nt];
        float i0=fsig(gA[0]), f0=fsig(gA[1]), g0=ftanh_(gA[2]), o0=fsig(gA[3]);
        float cA = f0*cregA[nt] + i0*g0; cregA[nt]=cA;
        float hA = o0*ftanh_(cA);
        if (nt < 8) hvA0[nt] = f2bf(hA); else hvA1[nt-8] = f2bf(hA);
        if (finA) { hnOut[(size_t)mbA*256u + jb + nt] = hA; cnOut[(size_t)mbA*256u + jb + nt] = cA; }
        f32x4 gB = accB[nt];
        float i1=fsig(gB[0]), f1=fsig(gB[1]), g1=ftanh_(gB[2]), o1=fsig(gB[3]);
        float cB = f1*cregB[nt] + i1*g1; cregB[nt]=cB;
        float hB = o1*ftanh_(cB);
        if (nt < 8) hvB0[nt] = f2bf(hB); else hvB1[nt-8] = f2bf(hB);
        if (finB) { hnOut[(size_t)mbB*256u + jb + nt] = hB; cnOut[(size_t)mbB*256u + jb + nt] = cB; }
      }
      // h -> A-tile (unconditional; inactive rows hold bounded garbage, unused)
      *(bf16x8*)(Alds + rA*768 + ((256 + jb2     ) ^ swc)) = hvA0;
      *(bf16x8*)(Alds + rA*768 + ((256 + jb2 + 16) ^ swc)) = hvA1;
      *(bf16x8*)(Alds + rB*768 + ((256 + jb2     ) ^ swc)) = hvB0;
      *(bf16x8*)(Alds + rB*768 + ((256 + jb2 + 16) ^ swc)) = hvB1;

      // next-step x into A-tile
      *(bf16x8*)(Alds + row8*768 + ((oct*32     ) ^ rsw8)) = xpre0;
      *(bf16x8*)(Alds + row8*768 + ((oct*32 + 16) ^ rsw8)) = xpre1;
    }

    // ---- final hidden store for rows whose segment ran to maxLen ----
    __syncthreads();
    if (maxLen > 0 && mln8 == (uint32_t)maxLen) {
      const size_t grow = (size_t)(mst8 + (uint32_t)(maxLen-1))*512u + mb8;
      short* hp = hidden + grow*256u + (size_t)oct*32u;
#pragma unroll
      for (int q=0;q<4;++q)
        *(bf16x8*)(hp + q*8) = *(const bf16x8*)(Alds + row8*768 + ((256 + oct*64 + q*16) ^ rsw8));
    }
  }
}

// ============================================================================
// K4 (split path): fused heads over dense hidden rows. 512 thr = 8 waves
// = (gq 0..3)x(rh 0..1); heads sequential (hd loop). 64 rows/block.
// ============================================================================
__global__ __launch_bounds__(512, 1) void k4_heads(
    const short* __restrict__ hidden,
    const short* __restrict__ wa1p, const short* __restrict__ wv1p,
    const short* __restrict__ wa2p, const short* __restrict__ wv2p,
    const float* __restrict__ ba1, const float* __restrict__ bv1,
    const float* __restrict__ ba2, const float* __restrict__ bv2,
    const float* __restrict__ wa3, const float* __restrict__ ba3,
    const float* __restrict__ wv3, const float* __restrict__ bv3,
    const unsigned char* __restrict__ maskB, const uint32_t* __restrict__ maskModePtr,
    float* __restrict__ logits, float* __restrict__ value)
{
  __shared__ char smem[67600];
  char* hidL = smem;                      // [64][512] swizzled
  char* hb1  = smem + 32768;              // [64][256]
  char* hb2  = smem + 49152;              // [64][256]
  float* w3L = (float*)(smem + 65536);    // [4][128]
  float* b3L = (float*)(smem + 67584);

  const int tid  = threadIdx.x;
  const int lane = tid & 63;
  const int wv   = tid >> 6;       // 0..7
  const int gq   = wv & 3;
  const int rh   = wv >> 2;
  const int cl   = lane & 15;
  const int u    = lane >> 4;
  const int ku   = u*16;
  const int swc  = (cl & 7) << 4;
  const int row8 = tid >> 3;       // 0..63
  const int oct  = tid & 7;
  const int rsw8 = (row8 & 7) << 4;
  const size_t r0 = (size_t)blockIdx.x * 64u;

  // stage hidden rows -> LDS (inverse of k3r's store layout)
  {
    const short* hp = hidden + (r0 + (size_t)row8)*256u + (size_t)oct*32u;
#pragma unroll
    for (int q=0;q<4;++q)
      *(bf16x8*)(hidL + row8*512 + ((oct*64 + q*16) ^ rsw8)) = *(const bf16x8*)(hp + q*8);
  }
  if (tid < 128) {
    w3L[tid]       = wa3[tid];
    w3L[128 + tid] = wa3[128 + tid];
    w3L[256 + tid] = wa3[256 + tid];
    w3L[384 + tid] = wv3[tid];
  }
  if (tid == 0) { b3L[0]=ba3[0]; b3L[1]=ba3[1]; b3L[2]=ba3[2]; b3L[3]=bv3[0]; }
  const uint32_t maskByteMode = *maskModePtr;
  const int* maskI = (const int*)maskB;
  __syncthreads();

  for (int hd = 0; hd < 2; ++hd) {
    const short* w1p = hd ? wv1p : wa1p;
    const short* w2p = hd ? wv2p : wa2p;
    const float* b1  = hd ? bv1 : ba1;
    const float* b2  = hd ? bv2 : ba2;

    // L1 (K=256): rows rh*32 + r4*16 + cl, n-slice gq*32 + n1*16 + u*4
    {
      f32x4 h1[2][2];
#pragma unroll
      for (int n1=0;n1<2;++n1){
        f32x4 bv = *(const f32x4*)(b1 + gq*32 + n1*16 + u*4);
        h1[n1][0]=bv; h1[n1][1]=bv;
      }
      for (int kt2=0; kt2<8; ++kt2) {
        bf16x8 bh[2];
#pragma unroll
        for (int r4=0;r4<2;++r4)
          bh[r4] = *(const bf16x8*)(hidL + (rh*32 + r4*16 + cl)*512 + ((kt2*64 + ku) ^ swc));
#pragma unroll
        for (int n1=0;n1<2;++n1) {
          const bf16x8 wf = *(const bf16x8*)(w1p + (size_t)(kt2*8 + gq*2 + n1)*512 + lane*8);
#pragma unroll
          for (int r4=0;r4<2;++r4)
            h1[n1][r4] = __builtin_amdgcn_mfma_f32_16x16x32_bf16(wf, bh[r4], h1[n1][r4], 0,0,0);
        }
      }
#pragma unroll
      for (int n1=0;n1<2;++n1){
#pragma unroll
        for (int r4=0;r4<2;++r4){
          bf16x4 hv;
#pragma unroll
          for (int e=0;e<4;++e) hv[e] = f2bf(ftanh_(h1[n1][r4][e]));
          int row = rh*32 + r4*16 + cl;
          *(bf16x4*)(hb1 + row*256 + ((2*(gq*32 + n1*16 + u*4)) ^ swc)) = hv;
        }
      }
    }
    __syncthreads();                 // hb1 ready

    // L2 (K=128)
    {
      f32x4 h2[2][2];
#pragma unroll
      for (int n1=0;n1<2;++n1){
        f32x4 bv = *(const f32x4*)(b2 + gq*32 + n1*16 + u*4);
        h2[n1][0]=bv; h2[n1][1]=bv;
      }
      for (int kt2=0; kt2<4; ++kt2) {
        bf16x8 bh[2];
#pragma unroll
        for (int r4=0;r4<2;++r4)
          bh[r4] = *(const bf16x8*)(hb1 + (rh*32 + r4*16 + cl)*256 + ((kt2*64 + ku) ^ swc));
#pragma unroll
        for (int n1=0;n1<2;++n1) {
          const bf16x8 wf = *(const bf16x8*)(w2p + (size_t)(kt2*8 + gq*2 + n1)*512 + lane*8);
#pragma unroll
          for (int r4=0;r4<2;++r4)
            h2[n1][r4] = __builtin_amdgcn_mfma_f32_16x16x32_bf16(wf, bh[r4], h2[n1][r4], 0,0,0);
        }
      }
#pragma unroll
      for (int n1=0;n1<2;++n1){
#pragma unroll
        for (int r4=0;r4<2;++r4){
          bf16x4 hv;
#pragma unroll
          for (int e=0;e<4;++e) hv[e] = f2bf(ftanh_(h2[n1][r4][e]));
          int row = rh*32 + r4*16 + cl;
          *(bf16x4*)(hb2 + row*256 + ((2*(gq*32 + n1*16 + u*4)) ^ swc)) = hv;
        }
      }
    }
    __syncthreads();                 // hb2 ready

    // final layer for this head
    {
      const int row  = tid >> 3;
      const int o    = (tid >> 1) & 3;
      const int half = tid & 1;
      const int sw   = (row&7)<<4;
      float s = half ? 0.0f : b3L[o];
      const float* wr = w3L + o*128 + half*64;
#pragma unroll
      for (int k16=0; k16<8; ++k16) {
        bf16x8 av = *(const bf16x8*)(hb2 + row*256 + (((half*8 + k16)*16) ^ sw));
#pragma unroll
        for (int j=0;j<8;++j) s += bf2f(av[j]) * wr[k16*8+j];
      }
      s += __shfl_xor(s, 1);
      if (half == 0) {
        const size_t grow = r0 + (size_t)row;
        if (hd == 0 && o < 3) {
          const size_t mi = grow*3u + (size_t)o;
          const bool masked = maskByteMode ? (maskB[mi] != 0) : (maskI[mi] != 0);
          logits[mi] = masked ? -1e8f : s;
        } else if (hd == 1 && o == 3) {
          value[grow] = s;
        }
      }
    }
    __syncthreads();                 // hb2/hb1 free for next head
  }
}

// ============================================================================
// K3 fused fallback (v4, proven): used when ws_size too small for hidden.
// ============================================================================
__global__ __launch_bounds__(512, 2) void k3_lstm_fused(
    const float* __restrict__ x, const int* __restrict__ done,
    const float* __restrict__ h0, const float* __restrict__ c0,
    const short* __restrict__ wpack, const float* __restrict__ bpack,
    const short* __restrict__ wa1p, const short* __restrict__ wv1p,
    const short* __restrict__ wa2p, const short* __restrict__ wv2p,
    const float* __restrict__ ba1, const float* __restrict__ bv1,
    const float* __restrict__ ba2, const float* __restrict__ bv2,
    const float* __restrict__ wa3, const float* __restrict__ ba3,
    const float* __restrict__ wv3, const float* __restrict__ bv3,
    const unsigned char* __restrict__ maskB,
    const uint32_t* __restrict__ maskModePtr,
    const uint32_t* __restrict__ sortedSegs, const uint32_t* __restrict__ nSegsPtr,
    float* __restrict__ logits, float* __restrict__ value,
    float* __restrict__ hnOut, float* __restrict__ cnOut)
{
  __shared__ char smem[121616];
  char* Alds = smem;
  char* hb1  = smem + 49152;
  char* hb2  = smem + 81920;
  float* biasL = (float*)(smem + 114688);
  uint32_t* meta = (uint32_t*)(smem + 118784);
  float* w3L = (float*)(smem + 119552);
  float* b3L = (float*)(smem + 121600);

  const int tid  = threadIdx.x;
  const int lane = tid & 63;
  const int wv   = tid >> 6;
  const int gq   = wv & 3;
  const int hd   = wv >> 2;
  const int cl   = lane & 15;
  const int u    = lane >> 4;
  const int ku   = u*16;
  const int swc  = (cl & 7) << 4;
  const int rA   = hd*32 + cl;
  const int rB   = rA + 16;
  const int jb   = gq*64 + u*16;
  const int jb2  = 2*jb;

  const int row8 = tid >> 3;
  const int oct  = tid & 7;
  const int rsw8 = (row8 & 7) << 4;

  biasL[tid]       = bpack[tid];
  biasL[512 + tid] = bpack[512 + tid];
  if (tid < 128) {
    w3L[tid]       = wa3[tid];
    w3L[128 + tid] = wa3[128 + tid];
    w3L[256 + tid] = wa3[256 + tid];
    w3L[384 + tid] = wv3[tid];
  }
  if (tid == 0) { b3L[0]=ba3[0]; b3L[1]=ba3[1]; b3L[2]=ba3[2]; b3L[3]=bv3[0]; }

  float4 bH1v[2], bH2v[2];
  {
    const float* b1 = hd ? bv1 : ba1;
    const float* b2 = hd ? bv2 : ba2;
#pragma unroll
    for (int n1=0; n1<2; ++n1) {
      bH1v[n1] = *(const float4*)(b1 + gq*32 + n1*16 + u*4);
      bH2v[n1] = *(const float4*)(b2 + gq*32 + n1*16 + u*4);
    }
  }
  const short* w1p = hd ? wv1p : wa1p;
  const short* w2p = hd ? wv2p : wa2p;

  const uint32_t maskByteMode = *maskModePtr;
  const int* maskI = (const int*)maskB;

  const uint32_t nSegs = *nSegsPtr;
  const uint32_t nGroups = (nSegs + 63u) >> 6;

  for (uint32_t g = blockIdx.x; g < nGroups; g += gridDim.x) {
    __syncthreads();
    if (tid < 64) {
      uint32_t idx = g*64u + (uint32_t)tid;
      uint32_t b=0, st=0, ln=0;
      if (idx < nSegs) {
        uint32_t r = sortedSegs[idx];
        b = r & 511u; st = (r>>9)&1023u; ln = ((r>>19)&1023u) + 1u;
      }
      meta[tid] = b; meta[64+tid] = st; meta[128+tid] = ln;
    }
    __syncthreads();

    const uint32_t mb8  = meta[row8];
    const uint32_t mst8 = meta[64+row8];
    const uint32_t mln8 = meta[128+row8];
    const uint32_t mbA  = meta[rA],    mbB  = meta[rB];
    const uint32_t mstA = meta[64+rA], mstB = meta[64+rB];
    const uint32_t mlnA = meta[128+rA],mlnB = meta[128+rB];
    const int maxLen = (int)meta[128];

    {
      const bool act = (mln8 > 0u);
      float xf[16];
      if (act) {
        const float4* xp = (const float4*)(x + ((size_t)mst8*512u + mb8)*128u + (size_t)oct*16u);
#pragma unroll
        for (int i=0;i<4;++i){ float4 t4 = xp[i]; xf[4*i]=t4.x; xf[4*i+1]=t4.y; xf[4*i+2]=t4.z; xf[4*i+3]=t4.w; }
      } else {
#pragma unroll
        for (int i=0;i<16;++i) xf[i]=0.0f;
      }
      bf16x8 v0, v1;
#pragma unroll
      for (int j=0;j<8;++j){ v0[j]=f2bf(xf[j]); v1[j]=f2bf(xf[8+j]); }
      *(bf16x8*)(Alds + row8*768 + ((oct*32     ) ^ rsw8)) = v0;
      *(bf16x8*)(Alds + row8*768 + ((oct*32 + 16) ^ rsw8)) = v1;

      const bool useInit = act && (mst8 == 0u) && (done[mb8] == 0);
      float hf[32];
      if (useInit) {
        const float4* hp = (const float4*)(h0 + (size_t)mb8*256u + (size_t)oct*32u);
#pragma unroll
        for (int i=0;i<8;++i){ float4 t4 = hp[i]; hf[4*i]=t4.x; hf[4*i+1]=t4.y; hf[4*i+2]=t4.z; hf[4*i+3]=t4.w; }
      } else {
#pragma unroll
        for (int i=0;i<32;++i) hf[i]=0.0f;
      }
#pragma unroll
      for (int q=0;q<4;++q){
        bf16x8 hv;
#pragma unroll
        for (int j=0;j<8;++j) hv[j]=f2bf(hf[q*8+j]);
        *(bf16x8*)(Alds + row8*768 + ((256 + oct*64 + q*16) ^ rsw8)) = hv;
      }
    }

    float cregA[16], cregB[16];
    {
      const bool initA = (mlnA > 0u) && (mstA == 0u) && (done[mbA] == 0);
      const bool initB = (mlnB > 0u) && (mstB == 0u) && (done[mbB] == 0);
      f32x4 ca[4], cb[4];
#pragma unroll
      for (int q=0;q<4;++q){
        ca[q] = initA ? *(const f32x4*)(c0 + (size_t)mbA*256u + jb + q*4) : (f32x4){0.f,0.f,0.f,0.f};
        cb[q] = initB ? *(const f32x4*)(c0 + (size_t)mbB*256u + jb + q*4) : (f32x4){0.f,0.f,0.f,0.f};
      }
#pragma unroll
      for (int nt=0;nt<16;++nt){ cregA[nt]=ca[nt>>2][nt&3]; cregB[nt]=cb[nt>>2][nt&3]; }
    }

    for (int it = 0; it < maxLen; ++it) {
      __syncthreads();

      f32x4 accA[16], accB[16];
#pragma unroll
      for (int nt=0;nt<16;++nt){
        f32x4 bv = *(const f32x4*)(biasL + gq*256 + nt*16 + u*4);
        accA[nt]=bv; accB[nt]=bv;
      }
      for (int kt=0; kt<12; ++kt) {
        if ((kt & 3) == 0) __builtin_amdgcn_s_barrier();
        const short* wkt = wpack + (size_t)(kt*4 + gq)*8192 + lane*8;
        bf16x8 bfA = *(const bf16x8*)(Alds + rA*768 + ((kt*64 + ku) ^ swc));
        bf16x8 bfB = *(const bf16x8*)(Alds + rB*768 + ((kt*64 + ku) ^ swc));
#pragma unroll
        for (int nt=0;nt<16;++nt) {
          const bf16x8 wf = *(const bf16x8*)(wkt + nt*512);
          accA[nt] = __builtin_amdgcn_mfma_f32_16x16x32_bf16(wf, bfA, accA[nt], 0,0,0);
          accB[nt] = __builtin_amdgcn_mfma_f32_16x16x32_bf16(wf, bfB, accB[nt], 0,0,0);
        }
      }

      float4 xq0,xq1,xq2,xq3;
      {
        const bool xact = (it + 1) < (int)mln8;
        if (xact) {
          const float4* xp = (const float4*)(x + ((size_t)(mst8+it+1u)*512u + mb8)*128u + (size_t)oct*16u);
          xq0=xp[0]; xq1=xp[1]; xq2=xp[2]; xq3=xp[3];
        } else {
          xq0=xq1=xq2=xq3=make_float4(0.f,0.f,0.f,0.f);
        }
      }

      __syncthreads();

      float hfA[16], hfB[16];
#pragma unroll
      for (int nt=0;nt<16;++nt) {
        f32x4 gA = accA[nt];
        float i0=fsig(gA[0]), f0=fsig(gA[1]), g0=ftanh_(gA[2]), o0=fsig(gA[3]);
        float cA = f0*cregA[nt] + i0*g0; cregA[nt]=cA; hfA[nt] = o0*ftanh_(cA);
        f32x4 gB = accB[nt];
        float i1=fsig(gB[0]), f1=fsig(gB[1]), g1=ftanh_(gB[2]), o1=fsig(gB[3]);
        float cB = f1*cregB[nt] + i1*g1; cregB[nt]=cB; hfB[nt] = o1*ftanh_(cB);
      }
      {
        bf16x8 hv0, hv1;
#pragma unroll
        for (int q=0;q<8;++q){ hv0[q]=f2bf(hfA[q]); hv1[q]=f2bf(hfA[8+q]); }
        *(bf16x8*)(Alds + rA*768 + ((256 + jb2     ) ^ swc)) = hv0;
        *(bf16x8*)(Alds + rA*768 + ((256 + jb2 + 16) ^ swc)) = hv1;
#pragma unroll
        for (int q=0;q<8;++q){ hv0[q]=f2bf(hfB[q]); hv1[q]=f2bf(hfB[8+q]); }
        *(bf16x8*)(Alds + rB*768 + ((256 + jb2     ) ^ swc)) = hv0;
        *(bf16x8*)(Alds + rB*768 + ((256 + jb2 + 16) ^ swc)) = hv1;
      }
      if ((it == (int)mlnA - 1) && (mstA + mlnA == 1024u)) {
        float4* hp4 = (float4*)(hnOut + (size_t)mbA*256u + jb);
        float4* cp4 = (float4*)(cnOut + (size_t)mbA*256u + jb);
#pragma unroll
        for (int q=0;q<4;++q){
          hp4[q] = make_float4(hfA[4*q],hfA[4*q+1],hfA[4*q+2],hfA[4*q+3]);
          cp4[q] = make_float4(cregA[4*q],cregA[4*q+1],cregA[4*q+2],cregA[4*q+3]);
        }
      }
      if ((it == (int)mlnB - 1) && (mstB + mlnB == 1024u)) {
        float4* hp4 = (float4*)(hnOut + (size_t)mbB*256u + jb);
        float4* cp4 = (float4*)(cnOut + (size_t)mbB*256u + jb);
#pragma unroll
        for (int q=0;q<4;++q){
          hp4[q] = make_float4(hfB[4*q],hfB[4*q+1],hfB[4*q+2],hfB[4*q+3]);
          cp4[q] = make_float4(cregB[4*q],cregB[4*q+1],cregB[4*q+2],cregB[4*q+3]);
        }
      }
      {
        float xf[16];
        xf[0]=xq0.x; xf[1]=xq0.y; xf[2]=xq0.z; xf[3]=xq0.w;
        xf[4]=xq1.x; xf[5]=xq1.y; xf[6]=xq1.z; xf[7]=xq1.w;
        xf[8]=xq2.x; xf[9]=xq2.y; xf[10]=xq2.z; xf[11]=xq2.w;
        xf[12]=xq3.x; xf[13]=xq3.y; xf[14]=xq3.z; xf[15]=xq3.w;
        bf16x8 v0, v1;
#pragma unroll
        for (int j=0;j<8;++j){ v0[j]=f2bf(xf[j]); v1[j]=f2bf(xf[8+j]); }
        *(bf16x8*)(Alds + row8*768 + ((oct*32     ) ^ rsw8)) = v0;
        *(bf16x8*)(Alds + row8*768 + ((oct*32 + 16) ^ rsw8)) = v1;
      }

      __syncthreads();

      {
        f32x4 h1[2][4];
#pragma unroll
        for (int n1=0;n1<2;++n1){
          f32x4 bv = {bH1v[n1].x, bH1v[n1].y, bH1v[n1].z, bH1v[n1].w};
#pragma unroll
          for (int r4=0;r4<4;++r4) h1[n1][r4] = bv;
        }
        for (int kt2=0; kt2<8; ++kt2) {
          bf16x8 bh[4];
#pragma unroll
          for (int r4=0;r4<4;++r4)
            bh[r4] = *(const bf16x8*)(Alds + (r4*16+cl)*768 + ((256 + kt2*64 + ku) ^ swc));
#pragma unroll
          for (int n1=0;n1<2;++n1) {
            const bf16x8 wf = *(const bf16x8*)(w1p + (size_t)(kt2*8 + gq*2 + n1)*512 + lane*8);
#pragma unroll
            for (int r4=0;r4<4;++r4)
              h1[n1][r4] = __builtin_amdgcn_mfma_f32_16x16x32_bf16(wf, bh[r4], h1[n1][r4], 0,0,0);
          }
        }
#pragma unroll
        for (int n1=0;n1<2;++n1){
#pragma unroll
          for (int r4=0;r4<4;++r4){
            bf16x4 hv;
#pragma unroll
            for (int e=0;e<4;++e) hv[e] = f2bf(ftanh_(h1[n1][r4][e]));
            int row = r4*16 + cl;
            *(bf16x4*)(hb1 + hd*16384 + row*256 + ((2*(gq*32 + n1*16 + u*4)) ^ swc)) = hv;
          }
        }
      }
      __syncthreads();

      {
        f32x4 h2[2][4];
#pragma unroll
        for (int n1=0;n1<2;++n1){
          f32x4 bv = {bH2v[n1].x, bH2v[n1].y, bH2v[n1].z, bH2v[n1].w};
#pragma unroll
          for (int r4=0;r4<4;++r4) h2[n1][r4] = bv;
        }
        const char* hbIn = hb1 + hd*16384;
        for (int kt2=0; kt2<4; ++kt2) {
          bf16x8 bh[4];
#pragma unroll
          for (int r4=0;r4<4;++r4)
            bh[r4] = *(const bf16x8*)(hbIn + (r4*16+cl)*256 + ((kt2*64 + ku) ^ swc));
#pragma unroll
          for (int n1=0;n1<2;++n1) {
            const bf16x8 wf = *(const bf16x8*)(w2p + (size_t)(kt2*8 + gq*2 + n1)*512 + lane*8);
#pragma unroll
            for (int r4=0;r4<4;++r4)
              h2[n1][r4] = __builtin_amdgcn_mfma_f32_16x16x32_bf16(wf, bh[r4], h2[n1][r4], 0,0,0);
          }
        }
#pragma unroll
        for (int n1=0;n1<2;++n1){
#pragma unroll
          for (int r4=0;r4<4;++r4){
            bf16x4 hv;
#pragma unroll
            for (int e=0;e<4;++e) hv[e] = f2bf(ftanh_(h2[n1][r4][e]));
            int row = r4*16 + cl;
            *(bf16x4*)(hb2 + hd*16384 + row*256 + ((2*(gq*32 + n1*16 + u*4)) ^ swc)) = hv;
          }
        }
      }
      __syncthreads();

      {
        const int frow = tid >> 3;
        const int o    = (tid >> 1) & 3;
        const int half = tid & 1;
        const uint32_t fmb  = meta[frow];
        const uint32_t fmst = meta[64+frow];
        const uint32_t fmln = meta[128+frow];
        const char* srcb = (o < 3) ? hb2 : (hb2 + 16384);
        const int sw = (frow&7)<<4;
        float s = half ? 0.0f : b3L[o];
        const float* wr = w3L + o*128 + half*64;
#pragma unroll
        for (int k16=0; k16<8; ++k16) {
          bf16x8 av = *(const bf16x8*)(srcb + frow*256 + (((half*8 + k16)*16) ^ sw));
#pragma unroll
          for (int j=0;j<8;++j) s += bf2f(av[j]) * wr[k16*8+j];
        }
        s += __shfl_xor(s, 1);
        if (half == 0 && it < (int)fmln) {
          const size_t grow = (size_t)((int)fmst + it)*512u + fmb;
          if (o < 3) {
            const size_t mi = grow*3u + (size_t)o;
            const bool masked = maskByteMode ? (maskB[mi] != 0) : (maskI[mi] != 0);
            logits[mi] = masked ? -1e8f : s;
          } else {
            value[grow] = s;
          }
        }
      }
    }
  }
}

// ============================================================================
extern "C" void kernel_launch(void* const* d_in, const int* in_sizes, int n_in,
                              void* d_out, int out_size, void* d_ws, size_t ws_size,
                              hipStream_t stream) {
  const float* x    = (const float*)d_in[0];
  const int*   done = (const int*)d_in[1];
  const unsigned char* mask = (const unsigned char*)d_in[2];
  const float* h0   = (const float*)d_in[3];
  const float* c0   = (const float*)d_in[4];
  const float* wih  = (const float*)d_in[5];
  const float* whh  = (const float*)d_in[6];
  const float* bih  = (const float*)d_in[7];
  const float* bhh  = (const float*)d_in[8];
  const float* wa1  = (const float*)d_in[9];
  const float* ba1  = (const float*)d_in[10];
  const float* wa2  = (const float*)d_in[11];
  const float* ba2  = (const float*)d_in[12];
  const float* wa3  = (const float*)d_in[13];
  const float* ba3  = (const float*)d_in[14];
  const float* wv1  = (const float*)d_in[15];
  const float* bv1  = (const float*)d_in[16];
  const float* wv2  = (const float*)d_in[17];
  const float* bv2  = (const float*)d_in[18];
  const float* wv3  = (const float*)d_in[19];
  const float* bv3  = (const float*)d_in[20];

  char* ws = (char*)d_ws;
  float* outLogits = (float*)d_out;                 // 524288*3
  float* outValue  = outLogits + 1572864;           // 524288
  float* outHn     = outValue  + 524288;            // 131072
  float* outCn     = outHn     + 131072;            // 131072

  hipMemsetAsync(ws + WS_META, 0, 16384, stream);

  k0a_packmain<<<96, 512, 0, stream>>>(wih, whh, bih, bhh,
      (short*)(ws + WS_WMAIN), (float*)(ws + WS_BMAIN));
  k0b_packheads<<<24, 512, 0, stream>>>(wa1, wv1, wa2, wv2,
      (short*)(ws + WS_WA1P), (short*)(ws + WS_WV1P),
      (short*)(ws + WS_WA2P), (short*)(ws + WS_WV2P));

  k1_maskmode<<<64, 256, 0, stream>>>(mask, (uint32_t*)(ws + WS_META + 16));

  k2a_segments<<<512, 256, 0, stream>>>(done, (uint32_t*)(ws + WS_SEGS),
                                        (uint32_t*)(ws + WS_META));
  k2b_hist<<<128, 512, 0, stream>>>((const uint32_t*)(ws + WS_SEGS),
      (const uint32_t*)(ws + WS_META), (uint32_t*)(ws + WS_META + 4096));
  k2c_scan<<<1, 1024, 0, stream>>>((const uint32_t*)(ws + WS_META + 4096),
      (uint32_t*)(ws + WS_META + 12288));
  k2d_scatter<<<128, 512, 0, stream>>>((const uint32_t*)(ws + WS_SEGS),
      (const uint32_t*)(ws + WS_META), (uint32_t*)(ws + WS_META + 12288),
      (uint32_t*)(ws + WS_SORTED));

  if (ws_size >= WS_NEED_SPLIT) {
    k3r_lstm<<<256, 512, 0, stream>>>(x, done, h0, c0,
        (const short*)(ws + WS_WMAIN), (const float*)(ws + WS_BMAIN),
        (const uint32_t*)(ws + WS_SORTED), (const uint32_t*)(ws + WS_META),
        (short*)(ws + WS_HID), outHn, outCn);
    k4_heads<<<8192, 512, 0, stream>>>((const short*)(ws + WS_HID),
        (const short*)(ws + WS_WA1P), (const short*)(ws + WS_WV1P),
        (const short*)(ws + WS_WA2P), (const short*)(ws + WS_WV2P),
        ba1, bv1, ba2, bv2, wa3, ba3, wv3, bv3,
        mask, (const uint32_t*)(ws + WS_META + 16),
        outLogits, outValue);
  } else {
    k3_lstm_fused<<<256, 512, 0, stream>>>(x, done, h0, c0,
        (const short*)(ws + WS_WMAIN), (const float*)(ws + WS_BMAIN),
        (const short*)(ws + WS_WA1P), (const short*)(ws + WS_WV1P),
        (const short*)(ws + WS_WA2P), (const short*)(ws + WS_WV2P),
        ba1, bv1, ba2, bv2, wa3, ba3, wv3, bv3,
        mask, (const uint32_t*)(ws + WS_META + 16),
        (const uint32_t*)(ws + WS_SORTED), (const uint32_t*)(ws + WS_META),
        outLogits, outValue, outHn, outCn);
  }

  (void)in_sizes; (void)n_in; (void)out_size;
}